// Round 2
// baseline (1080.045 us; speedup 1.0000x reference)
//
#include <hip/hip_runtime.h>

#define NN 20000
#define NE 640000

// ---------------------- edge-index dtype probe ------------------------------
// int64 data with values < 2^31 has every odd int32 word == 0. Genuine int32
// edge data has random node ids at odd positions (P(all 64 zero) ~ 1e-275).
__global__ void k_probe(const int* __restrict__ ei32, int* __restrict__ flag) {
  if (threadIdx.x == 0 && blockIdx.x == 0) {
    int allz = 1;
    for (int k = 0; k < 64; ++k)
      if (ei32[2 * k + 1] != 0) { allz = 0; break; }
    *flag = allz ? 2 : 1;  // stride in int32 words per logical element
  }
}

// ----------------------------- CSR build -----------------------------------
__global__ __launch_bounds__(256) void k_hist(const int* __restrict__ ei,
                                              const int* __restrict__ flag,
                                              int* __restrict__ cnt, int E) {
  int st = *flag;
  int e = blockIdx.x * 256 + threadIdx.x;
  if (e < E) atomicAdd(&cnt[ei[(size_t)(E + e) * st]], 1);
}

__global__ __launch_bounds__(1024) void k_scan(int* __restrict__ cur,
                                               int* __restrict__ rowptr,
                                               float* __restrict__ invdeg,
                                               int N, int E) {
  __shared__ int lds[1024];
  int tid = threadIdx.x;
  const int CH = (N + 1023) / 1024;
  int base = tid * CH;
  int s = 0;
  for (int c = 0; c < CH; ++c) { int i = base + c; if (i < N) s += cur[i]; }
  lds[tid] = s;
  __syncthreads();
  for (int off = 1; off < 1024; off <<= 1) {
    int v = (tid >= off) ? lds[tid - off] : 0;
    __syncthreads();
    lds[tid] += v;
    __syncthreads();
  }
  int run = (tid == 0) ? 0 : lds[tid - 1];
  for (int c = 0; c < CH; ++c) {
    int i = base + c; if (i >= N) break;
    int dg = cur[i];
    rowptr[i] = run;
    cur[i] = run;                       // cursor for scatter
    invdeg[i] = 1.0f / (float)(dg < 1 ? 1 : dg);
    run += dg;
  }
  if (tid == 0) rowptr[N] = E;
}

__global__ __launch_bounds__(256) void k_scatter(const int* __restrict__ ei,
                                                 const int* __restrict__ flag,
                                                 int* __restrict__ cur,
                                                 int* __restrict__ csr, int E) {
  int st = *flag;
  int e = blockIdx.x * 256 + threadIdx.x;
  if (e < E) {
    int d = ei[(size_t)(E + e) * st];
    int p = atomicAdd(&cur[d], 1);
    csr[p] = ei[(size_t)e * st];
  }
}

// ------------------------ weight transpose (concat) -------------------------
// out[w*C + u] = u<dh ? A[u*K+w] : B[(u-dh)*K+w];  C = (B? 2dh : dh)
__global__ __launch_bounds__(256) void k_wtrans(const float* __restrict__ A,
                                                const float* __restrict__ B,
                                                float* __restrict__ out,
                                                int dh, int K) {
  int C = B ? 2 * dh : dh;
  int total = K * C;
  int idx = blockIdx.x * 256 + threadIdx.x;
  if (idx >= total) return;
  int w = idx / C, u = idx - w * C;
  out[idx] = (u < dh) ? A[u * K + w] : B[(u - dh) * K + w];
}

// ------------------- conv composite operator build --------------------------
// CBp[ky2][ky1][u][i][jq] : conv3 o conv2 partial, banded |q-u|<=2
__global__ __launch_bounds__(256) void k_cbp(const float* __restrict__ Wc2,
                                             const float* __restrict__ Wc3,
                                             float* __restrict__ CBp) {
  int idx = blockIdx.x * 256 + threadIdx.x;
  if (idx >= 184320) return;
  int jq = idx % 5;
  int i  = (idx / 5) % 64;
  int u  = (idx / 320) % 64;
  int d1 = (idx / 20480) % 3;   // ky of conv2
  int d2 = idx / 61440;         // ky of conv3
  int q = u + jq - 2;
  float s = 0.0f;
  if (q >= 0 && q < 64) {
    for (int dl2 = -1; dl2 <= 1; ++dl2) {
      int p = u + dl2; if ((unsigned)p >= 64u) continue;
      int dl1 = q - p; if (dl1 < -1 || dl1 > 1) continue;
      const float* w3 = Wc3 + d2 * 3 + (dl2 + 1);          // + o*9
      const float* w2 = Wc2 + i * 9 + d1 * 3 + (dl1 + 1);  // + o*576
      for (int o = 0; o < 64; ++o) s += w3[o * 9] * w2[o * 576];
    }
  }
  CBp[idx] = s;
}

__device__ __forceinline__ bool maskB(int var, int o2, int o1) {
  int s = o2 + o1;
  switch (var) {
    case 0: return (o2 >= 0) && (s >= 0);
    case 1: return s >= -1;
    case 3: return s <= 1;
    case 4: return (o2 <= 0) && (s <= 0);
    default: return true;
  }
}

// M5[var][d][u][jw], banded |w-u|<=3; residual identity folded in at d=3,jw=3
__global__ __launch_bounds__(256) void k_m5(const float* __restrict__ CBp,
                                            const float* __restrict__ Wc1,
                                            float* __restrict__ M5) {
  int idx = blockIdx.x * 256 + threadIdx.x;
  if (idx >= 15680) return;
  int jw = idx % 7;
  int u  = (idx / 7) % 64;
  int d  = (idx / 448) % 7;
  int var = idx / 3136;
  int w = u + jw - 3;
  float s = 0.0f;
  if (w >= 0 && w < 64) {
    for (int ky2 = 0; ky2 < 3; ++ky2)
      for (int ky1 = 0; ky1 < 3; ++ky1) {
        int o2 = ky2 - 1, o1 = ky1 - 1;
        if (!maskB(var, o2, o1)) continue;
        int o0 = (d - 3) - o2 - o1;
        if (o0 < -1 || o0 > 1) continue;
        int ky0 = o0 + 1;
        for (int jq = 0; jq < 5; ++jq) {
          int q = u + jq - 2; if ((unsigned)q >= 64u) continue;
          int kx0 = w - q + 1; if ((unsigned)kx0 >= 3u) continue;
          const float* cb = CBp + (size_t)(((ky2 * 3 + ky1) * 64 + u) * 64) * 5 + jq;
          const float* w1 = Wc1 + ky0 * 3 + kx0;  // + i*9
          float t = 0.0f;
          for (int i = 0; i < 64; ++i) t += cb[i * 5] * w1[i * 9];
          s += t;
        }
      }
  }
  if (d == 3 && jw == 3) s += 1.0f;  // residual: out = conv(h) + h (ONLY here)
  M5[idx] = s;
}

// beta5[var][u]: bias propagation through the conv stack (with truncations)
__global__ __launch_bounds__(320) void k_beta(const float* __restrict__ Wc2,
                                              const float* __restrict__ Wc3,
                                              const float* __restrict__ bc1,
                                              const float* __restrict__ bc2,
                                              const float* __restrict__ bc3,
                                              float* __restrict__ beta5) {
  __shared__ float S2[576];  // S2[o][ky][kx] = sum_i Wc2[o,i,ky,kx]*bc1[i]
  int tid = threadIdx.x;
  for (int e = tid; e < 576; e += 320) {
    int o = e / 9, r = e - o * 9;
    float t = 0.0f;
    for (int i = 0; i < 64; ++i) t += Wc2[o * 576 + i * 9 + r] * bc1[i];
    S2[e] = t;
  }
  __syncthreads();
  int var = tid / 64, u = tid % 64;
  float s = bc3[0];
  for (int ky2 = 0; ky2 < 3; ++ky2) {
    int o2 = ky2 - 1;
    bool okA = (var == 0) ? (o2 >= 0) : (var == 4) ? (o2 <= 0) : true;
    if (!okA) continue;
    for (int dl2 = -1; dl2 <= 1; ++dl2) {
      int p = u + dl2; if ((unsigned)p >= 64u) continue;
      for (int o = 0; o < 64; ++o) {
        float inner = bc2[o];
        for (int ky1 = 0; ky1 < 3; ++ky1) {
          int o1 = ky1 - 1;
          if (!maskB(var, o2, o1)) continue;
          for (int dl1 = -1; dl1 <= 1; ++dl1) {
            int pq = p + dl1; if ((unsigned)pq >= 64u) continue;
            inner += S2[o * 9 + ky1 * 3 + (dl1 + 1)];
          }
        }
        s += Wc3[o * 9 + ky2 * 3 + (dl2 + 1)] * inner;
      }
    }
  }
  beta5[var * 64 + u] = s;
}

// ----------------------------- dense GEMM -----------------------------------
// out[N x C] = X[N x K] @ Wt[K x C] (+ bias). 64-row tile per block.
template <int C, int K>
__global__ __launch_bounds__(256) void k_gemm(const float* __restrict__ X,
                                              const float* __restrict__ Wt,
                                              const float* __restrict__ bias,
                                              float* __restrict__ out, int N) {
  constexpr int RPT = (C * 64) / 256;  // rows per thread
  __shared__ float Xs[64 * K];
  int y0 = blockIdx.x * 64;
  for (int idx = threadIdx.x; idx < 64 * K; idx += 256) {
    int r = idx / K, w = idx - r * K;
    int y = y0 + r;
    Xs[idx] = (y < N) ? X[(size_t)y * K + w] : 0.0f;
  }
  __syncthreads();
  int u = threadIdx.x % C;
  int rg = threadIdx.x / C;
  float acc[RPT];
  float bv = bias ? bias[u] : 0.0f;
#pragma unroll
  for (int k = 0; k < RPT; ++k) acc[k] = bv;
  for (int w0 = 0; w0 < K; w0 += 4) {
    float m0 = Wt[(w0 + 0) * C + u];
    float m1 = Wt[(w0 + 1) * C + u];
    float m2 = Wt[(w0 + 2) * C + u];
    float m3 = Wt[(w0 + 3) * C + u];
    const float* xs = &Xs[(rg * RPT) * K + w0];
#pragma unroll
    for (int k = 0; k < RPT; ++k) {
      float4 h = *(const float4*)(xs + k * K);
      acc[k] += m0 * h.x + m1 * h.y + m2 * h.z + m3 * h.w;
    }
  }
#pragma unroll
  for (int k = 0; k < RPT; ++k) {
    int y = y0 + rg * RPT + k;
    if (y < N) out[(size_t)y * C + u] = acc[k];
  }
}

// --------------------------- mean aggregation -------------------------------
// out[i][f] = invdeg[i]*sum_{j in CSR(i)} yz[src_j][f] + bl[f] + yz[i][dh+f]
__global__ __launch_bounds__(256) void k_agg(const float* __restrict__ yz,
                                             const int* __restrict__ csr,
                                             const int* __restrict__ rowptr,
                                             const float* __restrict__ invdeg,
                                             const float* __restrict__ bl,
                                             float* __restrict__ out,
                                             int N, int dh) {
  int node = blockIdx.x * 4 + (threadIdx.x >> 6);
  int lane = threadIdx.x & 63;
  if (node >= N) return;
  int S = 2 * dh;
  int beg = rowptr[node], end = rowptr[node + 1];
  if (lane < dh) {
    float acc = 0.0f;
    int j = beg;
    for (; j + 3 < end; j += 4) {
      int s0 = csr[j], s1 = csr[j + 1], s2 = csr[j + 2], s3 = csr[j + 3];
      float a0 = yz[(size_t)s0 * S + lane];
      float a1 = yz[(size_t)s1 * S + lane];
      float a2 = yz[(size_t)s2 * S + lane];
      float a3 = yz[(size_t)s3 * S + lane];
      acc += a0 + a1 + a2 + a3;
    }
    for (; j < end; ++j) acc += yz[(size_t)csr[j] * S + lane];
    out[(size_t)node * dh + lane] =
        acc * invdeg[node] + bl[lane] + yz[(size_t)node * S + dh + lane];
  }
}

// --------------------- conv composite apply (+residual) ---------------------
// out[y][u] = beta5[var][u] + sum_{d,jw} M5[var][d][u][jw]*h[y+d-3][u+jw-3]
// (residual identity is folded into M5 at d=3,jw=3 — do NOT add h again)
__global__ __launch_bounds__(256) void k_apply(const float* __restrict__ h,
                                               const float* __restrict__ M5,
                                               const float* __restrict__ beta5,
                                               float* __restrict__ out, int N) {
  int gid = blockIdx.x * 256 + threadIdx.x;
  int y = gid >> 6, u = gid & 63;
  if (y >= N) return;
  int var = (y == 0) ? 0 : (y == 1) ? 1 : (y == N - 2) ? 3 : (y == N - 1) ? 4 : 2;
  float acc = beta5[var * 64 + u];
#pragma unroll
  for (int d = 0; d < 7; ++d) {
    int yy = y + d - 3;
    if ((unsigned)yy >= (unsigned)N) continue;
    const float* hr = h + (size_t)yy * 64;
    const float* mr = M5 + ((var * 7 + d) * 64 + u) * 7;
#pragma unroll
    for (int jw = 0; jw < 7; ++jw) {
      int w = u + jw - 3;
      if ((unsigned)w < 64u) acc += mr[jw] * hr[w];
    }
  }
  out[(size_t)y * 64 + u] = acc;
}

// ------------------------------- launcher -----------------------------------
extern "C" void kernel_launch(void* const* d_in, const int* in_sizes, int n_in,
                              void* d_out, int out_size, void* d_ws, size_t ws_size,
                              hipStream_t stream) {
  const int N = NN, E = NE;
  const float* x   = (const float*)d_in[0];
  const int*   ei  = (const int*)d_in[1];
  const float* Wl1 = (const float*)d_in[2];
  const float* bl1 = (const float*)d_in[3];
  const float* Wr1 = (const float*)d_in[4];
  const float* Wl2 = (const float*)d_in[5];
  const float* bl2 = (const float*)d_in[6];
  const float* Wr2 = (const float*)d_in[7];
  const float* Wl3 = (const float*)d_in[8];
  const float* bl3 = (const float*)d_in[9];
  const float* Wr3 = (const float*)d_in[10];
  const float* Wc1 = (const float*)d_in[11];
  const float* bc1 = (const float*)d_in[12];
  const float* Wc2 = (const float*)d_in[13];
  const float* bc2 = (const float*)d_in[14];
  const float* Wc3 = (const float*)d_in[15];
  const float* bc3 = (const float*)d_in[16];
  const float* W2  = (const float*)d_in[17];
  const float* b2  = (const float*)d_in[18];

  char* ws = (char*)d_ws;
  size_t off = 0;
  auto alloc = [&](size_t bytes) -> void* {
    off = (off + 255) & ~(size_t)255;
    void* p = ws + off;
    off += bytes;
    return p;
  };
  int*   eflag  = (int*)alloc(4);
  int*   rowptr = (int*)alloc((size_t)(N + 1) * 4);
  int*   cursor = (int*)alloc((size_t)N * 4);
  float* invdeg = (float*)alloc((size_t)N * 4);
  int*   csr    = (int*)alloc((size_t)E * 4);
  float* Wt1    = (float*)alloc(128 * 128 * 4);
  float* Wt2    = (float*)alloc(64 * 128 * 4);
  float* Wt3    = (float*)alloc(64 * 64 * 4);
  float* W2t    = (float*)alloc(64 * 64 * 4);
  float* CBp    = (float*)alloc(184320 * 4);
  float* M5     = (float*)alloc(15680 * 4);
  float* beta5  = (float*)alloc(320 * 4);
  float* yz     = (float*)alloc((size_t)N * 128 * 4);  // also reused as conv out
  float* hA     = (float*)alloc((size_t)N * 64 * 4);
  float* hB     = (float*)alloc((size_t)N * 64 * 4);
  (void)ws_size; (void)in_sizes; (void)n_in; (void)out_size;

  const int gE = (E + 255) / 256;       // 2500
  const int gG = (N + 63) / 64;         // 313
  const int gA = (N + 3) / 4;           // 5000
  const int gP = (N * 64 + 255) / 256;  // 5000

  // CSR build (once; shared by all 6 sage layers)
  k_probe<<<1, 64, 0, stream>>>(ei, eflag);
  hipMemsetAsync(cursor, 0, (size_t)N * 4, stream);
  k_hist<<<gE, 256, 0, stream>>>(ei, eflag, cursor, E);
  k_scan<<<1, 1024, 0, stream>>>(cursor, rowptr, invdeg, N, E);
  k_scatter<<<gE, 256, 0, stream>>>(ei, eflag, cursor, csr, E);

  // weight transposes
  k_wtrans<<<(128 * 128 + 255) / 256, 256, 0, stream>>>(Wl1, Wr1, Wt1, 64, 128);
  k_wtrans<<<(64 * 128 + 255) / 256, 256, 0, stream>>>(Wl2, Wr2, Wt2, 64, 64);
  k_wtrans<<<(64 * 64 + 255) / 256, 256, 0, stream>>>(Wl3, Wr3, Wt3, 32, 64);
  k_wtrans<<<(64 * 64 + 255) / 256, 256, 0, stream>>>(W2, nullptr, W2t, 64, 64);

  // conv composite operator build
  k_cbp<<<720, 256, 0, stream>>>(Wc2, Wc3, CBp);
  k_m5<<<62, 256, 0, stream>>>(CBp, Wc1, M5);
  k_beta<<<1, 320, 0, stream>>>(Wc2, Wc3, bc1, bc2, bc3, beta5);

  // sage1: x[ N x128 ] -> yz (y|z), agg -> hA
  k_gemm<128, 128><<<gG, 256, 0, stream>>>(x, Wt1, nullptr, yz, N);
  k_agg<<<gA, 256, 0, stream>>>(yz, csr, rowptr, invdeg, bl1, hA, N, 64);
  // sage2: hA -> hB
  k_gemm<128, 64><<<gG, 256, 0, stream>>>(hA, Wt2, nullptr, yz, N);
  k_agg<<<gA, 256, 0, stream>>>(yz, csr, rowptr, invdeg, bl2, hB, N, 64);
  // sage3: hB -> hA
  k_gemm<128, 64><<<gG, 256, 0, stream>>>(hB, Wt2, nullptr, yz, N);
  k_agg<<<gA, 256, 0, stream>>>(yz, csr, rowptr, invdeg, bl2, hA, N, 64);

  // conv stack + residual (composite banded operator), into yz (reused)
  k_apply<<<gP, 256, 0, stream>>>(hA, M5, beta5, yz, N);
  // linear2: yz -> hB
  k_gemm<64, 64><<<gG, 256, 0, stream>>>(yz, W2t, b2, hB, N);

  // sage4: hB -> hA
  k_gemm<128, 64><<<gG, 256, 0, stream>>>(hB, Wt2, nullptr, yz, N);
  k_agg<<<gA, 256, 0, stream>>>(yz, csr, rowptr, invdeg, bl2, hA, N, 64);
  // sage5: hA -> hB
  k_gemm<128, 64><<<gG, 256, 0, stream>>>(hA, Wt2, nullptr, yz, N);
  k_agg<<<gA, 256, 0, stream>>>(yz, csr, rowptr, invdeg, bl2, hB, N, 64);
  // sage6: hB -> d_out (32-dim)
  k_gemm<64, 64><<<gG, 256, 0, stream>>>(hB, Wt3, nullptr, yz, N);
  k_agg<<<gA, 256, 0, stream>>>(yz, csr, rowptr, invdeg, bl3, (float*)d_out, N, 32);
}

// Round 3
// 704.255 us; speedup vs baseline: 1.5336x; 1.5336x over previous
//
#include <hip/hip_runtime.h>

#define NN 20000
#define NE 640000

// ---------------------- edge-index dtype probe ------------------------------
// int64 data with values < 2^31 has every odd int32 word == 0. Genuine int32
// edge data has random node ids at odd positions (P(all 64 zero) ~ 1e-275).
__global__ void k_probe(const int* __restrict__ ei32, int* __restrict__ flag) {
  int lane = threadIdx.x & 63;
  int v = ei32[2 * lane + 1];
  unsigned long long nz = __ballot(v != 0);
  if (lane == 0) *flag = (nz == 0ull) ? 2 : 1;  // words per logical element
}

// ----------------------------- CSR build -----------------------------------
__global__ __launch_bounds__(256) void k_hist(const int* __restrict__ ei,
                                              const int* __restrict__ flag,
                                              int* __restrict__ cnt, int E) {
  int st = *flag;
  int e = blockIdx.x * 256 + threadIdx.x;
  if (e < E) atomicAdd(&cnt[ei[(size_t)(E + e) * st]], 1);
}

__global__ __launch_bounds__(1024) void k_scan(int* __restrict__ cur,
                                               int* __restrict__ rowptr,
                                               float* __restrict__ invdeg,
                                               int N, int E) {
  __shared__ int lds[1024];
  int tid = threadIdx.x;
  const int CH = (N + 1023) / 1024;
  int base = tid * CH;
  int s = 0;
  for (int c = 0; c < CH; ++c) { int i = base + c; if (i < N) s += cur[i]; }
  lds[tid] = s;
  __syncthreads();
  for (int off = 1; off < 1024; off <<= 1) {
    int v = (tid >= off) ? lds[tid - off] : 0;
    __syncthreads();
    lds[tid] += v;
    __syncthreads();
  }
  int run = (tid == 0) ? 0 : lds[tid - 1];
  for (int c = 0; c < CH; ++c) {
    int i = base + c; if (i >= N) break;
    int dg = cur[i];
    rowptr[i] = run;
    cur[i] = run;                       // cursor for scatter
    invdeg[i] = 1.0f / (float)(dg < 1 ? 1 : dg);
    run += dg;
  }
  if (tid == 0) rowptr[N] = E;
}

__global__ __launch_bounds__(256) void k_scatter(const int* __restrict__ ei,
                                                 const int* __restrict__ flag,
                                                 int* __restrict__ cur,
                                                 int* __restrict__ csr, int E) {
  int st = *flag;
  int e = blockIdx.x * 256 + threadIdx.x;
  if (e < E) {
    int d = ei[(size_t)(E + e) * st];
    int p = atomicAdd(&cur[d], 1);
    csr[p] = ei[(size_t)e * st];
  }
}

// ------------------------ weight transpose (concat) -------------------------
// out[w*C + u] = u<dh ? A[u*K+w] : B[(u-dh)*K+w];  C = (B? 2dh : dh)
__global__ __launch_bounds__(256) void k_wtrans(const float* __restrict__ A,
                                                const float* __restrict__ B,
                                                float* __restrict__ out,
                                                int dh, int K) {
  int C = B ? 2 * dh : dh;
  int total = K * C;
  int idx = blockIdx.x * 256 + threadIdx.x;
  if (idx >= total) return;
  int w = idx / C, u = idx - w * C;
  out[idx] = (u < dh) ? A[u * K + w] : B[(u - dh) * K + w];
}

// ------------------- conv composite operator build --------------------------
// CBp[ky2][ky1][u][i][jq] : conv3 o conv2 partial, banded |q-u|<=2
__global__ __launch_bounds__(256) void k_cbp(const float* __restrict__ Wc2,
                                             const float* __restrict__ Wc3,
                                             float* __restrict__ CBp) {
  int idx = blockIdx.x * 256 + threadIdx.x;
  if (idx >= 184320) return;
  int jq = idx % 5;
  int i  = (idx / 5) % 64;
  int u  = (idx / 320) % 64;
  int d1 = (idx / 20480) % 3;   // ky of conv2
  int d2 = idx / 61440;         // ky of conv3
  int q = u + jq - 2;
  float s = 0.0f;
  if (q >= 0 && q < 64) {
    for (int dl2 = -1; dl2 <= 1; ++dl2) {
      int p = u + dl2; if ((unsigned)p >= 64u) continue;
      int dl1 = q - p; if (dl1 < -1 || dl1 > 1) continue;
      const float* w3 = Wc3 + d2 * 3 + (dl2 + 1);          // + o*9
      const float* w2 = Wc2 + i * 9 + d1 * 3 + (dl1 + 1);  // + o*576
      for (int o = 0; o < 64; ++o) s += w3[o * 9] * w2[o * 576];
    }
  }
  CBp[idx] = s;
}

__device__ __forceinline__ bool maskB(int var, int o2, int o1) {
  int s = o2 + o1;
  switch (var) {
    case 0: return (o2 >= 0) && (s >= 0);
    case 1: return s >= -1;
    case 3: return s <= 1;
    case 4: return (o2 <= 0) && (s <= 0);
    default: return true;
  }
}

// M5[var][d][u][jw], banded |w-u|<=3; residual identity folded in at d=3,jw=3
__global__ __launch_bounds__(256) void k_m5(const float* __restrict__ CBp,
                                            const float* __restrict__ Wc1,
                                            float* __restrict__ M5) {
  int idx = blockIdx.x * 256 + threadIdx.x;
  if (idx >= 15680) return;
  int jw = idx % 7;
  int u  = (idx / 7) % 64;
  int d  = (idx / 448) % 7;
  int var = idx / 3136;
  int w = u + jw - 3;
  float s = 0.0f;
  if (w >= 0 && w < 64) {
    for (int ky2 = 0; ky2 < 3; ++ky2)
      for (int ky1 = 0; ky1 < 3; ++ky1) {
        int o2 = ky2 - 1, o1 = ky1 - 1;
        if (!maskB(var, o2, o1)) continue;
        int o0 = (d - 3) - o2 - o1;
        if (o0 < -1 || o0 > 1) continue;
        int ky0 = o0 + 1;
        for (int jq = 0; jq < 5; ++jq) {
          int q = u + jq - 2; if ((unsigned)q >= 64u) continue;
          int kx0 = w - q + 1; if ((unsigned)kx0 >= 3u) continue;
          const float* cb = CBp + (size_t)(((ky2 * 3 + ky1) * 64 + u) * 64) * 5 + jq;
          const float* w1 = Wc1 + ky0 * 3 + kx0;  // + i*9
          float t = 0.0f;
          for (int i = 0; i < 64; ++i) t += cb[i * 5] * w1[i * 9];
          s += t;
        }
      }
  }
  if (d == 3 && jw == 3) s += 1.0f;  // residual: out = conv(h) + h (ONLY here)
  M5[idx] = s;
}

// beta5[var][u]: bias propagation through the conv stack (with truncations).
// 5 blocks (one per variant) x 256 threads (u = tid&63, o-chunk = tid>>6).
// All main-loop reads are LDS wave-uniform broadcasts.
__global__ __launch_bounds__(256) void k_beta(const float* __restrict__ Wc2,
                                              const float* __restrict__ Wc3,
                                              const float* __restrict__ bc1,
                                              const float* __restrict__ bc2,
                                              const float* __restrict__ bc3,
                                              float* __restrict__ beta5) {
  __shared__ float S2[576];  // S2[o][ky][kx] = sum_i Wc2[o,i,ky,kx]*bc1[i]
  __shared__ float W3[576];
  __shared__ float B2[64];
  __shared__ float part[256];
  int tid = threadIdx.x;
  int var = blockIdx.x;
  for (int e = tid; e < 576; e += 256) {
    int o = e / 9, r = e - o * 9;
    float t = 0.0f;
    for (int i = 0; i < 64; ++i) t += Wc2[o * 576 + i * 9 + r] * bc1[i];
    S2[e] = t;
    W3[e] = Wc3[e];
  }
  if (tid < 64) B2[tid] = bc2[tid];
  __syncthreads();
  int u = tid & 63, oc = tid >> 6;
  float s = 0.0f;
  for (int ky2 = 0; ky2 < 3; ++ky2) {
    int o2 = ky2 - 1;
    bool okA = (var == 0) ? (o2 >= 0) : (var == 4) ? (o2 <= 0) : true;
    if (!okA) continue;
    for (int dl2 = -1; dl2 <= 1; ++dl2) {
      int p = u + dl2; if ((unsigned)p >= 64u) continue;
      float sel[9];
#pragma unroll
      for (int ky1 = 0; ky1 < 3; ++ky1) {
        int o1 = ky1 - 1;
        bool mb = maskB(var, o2, o1);
#pragma unroll
        for (int dl1 = -1; dl1 <= 1; ++dl1) {
          int pq = p + dl1;
          sel[ky1 * 3 + dl1 + 1] = (mb && (unsigned)pq < 64u) ? 1.0f : 0.0f;
        }
      }
#pragma unroll 4
      for (int oo = 0; oo < 16; ++oo) {
        int o = oc * 16 + oo;
        float inner = B2[o];
#pragma unroll
        for (int r = 0; r < 9; ++r) inner += S2[o * 9 + r] * sel[r];
        s += W3[o * 9 + ky2 * 3 + (dl2 + 1)] * inner;
      }
    }
  }
  part[tid] = s;
  __syncthreads();
  if (tid < 64) {
    beta5[var * 64 + tid] =
        bc3[0] + part[tid] + part[64 + tid] + part[128 + tid] + part[192 + tid];
  }
}

// ----------------------------- dense GEMM -----------------------------------
// out[N x C] = X[N x K] @ Wt[K x C] (+ bias). 64-row tile per block.
template <int C, int K>
__global__ __launch_bounds__(256) void k_gemm(const float* __restrict__ X,
                                              const float* __restrict__ Wt,
                                              const float* __restrict__ bias,
                                              float* __restrict__ out, int N) {
  constexpr int RPT = (C * 64) / 256;  // rows per thread
  __shared__ float Xs[64 * K];
  int y0 = blockIdx.x * 64;
  for (int idx = threadIdx.x; idx < 64 * K; idx += 256) {
    int r = idx / K, w = idx - r * K;
    int y = y0 + r;
    Xs[idx] = (y < N) ? X[(size_t)y * K + w] : 0.0f;
  }
  __syncthreads();
  int u = threadIdx.x % C;
  int rg = threadIdx.x / C;
  float acc[RPT];
  float bv = bias ? bias[u] : 0.0f;
#pragma unroll
  for (int k = 0; k < RPT; ++k) acc[k] = bv;
  for (int w0 = 0; w0 < K; w0 += 4) {
    float m0 = Wt[(w0 + 0) * C + u];
    float m1 = Wt[(w0 + 1) * C + u];
    float m2 = Wt[(w0 + 2) * C + u];
    float m3 = Wt[(w0 + 3) * C + u];
    const float* xs = &Xs[(rg * RPT) * K + w0];
#pragma unroll
    for (int k = 0; k < RPT; ++k) {
      float4 h = *(const float4*)(xs + k * K);
      acc[k] += m0 * h.x + m1 * h.y + m2 * h.z + m3 * h.w;
    }
  }
#pragma unroll
  for (int k = 0; k < RPT; ++k) {
    int y = y0 + rg * RPT + k;
    if (y < N) out[(size_t)y * C + u] = acc[k];
  }
}

// --------------------------- mean aggregation -------------------------------
// out[i][f] = invdeg[i]*sum_{j in CSR(i)} yz[src_j][f] + bl[f] + yz[i][dh+f]
__global__ __launch_bounds__(256) void k_agg(const float* __restrict__ yz,
                                             const int* __restrict__ csr,
                                             const int* __restrict__ rowptr,
                                             const float* __restrict__ invdeg,
                                             const float* __restrict__ bl,
                                             float* __restrict__ out,
                                             int N, int dh) {
  int node = blockIdx.x * 4 + (threadIdx.x >> 6);
  int lane = threadIdx.x & 63;
  if (node >= N) return;
  int S = 2 * dh;
  int beg = rowptr[node], end = rowptr[node + 1];
  if (lane < dh) {
    float acc = 0.0f;
    int j = beg;
    for (; j + 3 < end; j += 4) {
      int s0 = csr[j], s1 = csr[j + 1], s2 = csr[j + 2], s3 = csr[j + 3];
      float a0 = yz[(size_t)s0 * S + lane];
      float a1 = yz[(size_t)s1 * S + lane];
      float a2 = yz[(size_t)s2 * S + lane];
      float a3 = yz[(size_t)s3 * S + lane];
      acc += a0 + a1 + a2 + a3;
    }
    for (; j < end; ++j) acc += yz[(size_t)csr[j] * S + lane];
    out[(size_t)node * dh + lane] =
        acc * invdeg[node] + bl[lane] + yz[(size_t)node * S + dh + lane];
  }
}

// --------------------- conv composite apply (+residual) ---------------------
// out[y][u] = beta5[var][u] + sum_{d,jw} M5[var][d][u][jw]*h[y+d-3][u+jw-3]
// (residual identity is folded into M5 at d=3,jw=3 — do NOT add h again)
__global__ __launch_bounds__(256) void k_apply(const float* __restrict__ h,
                                               const float* __restrict__ M5,
                                               const float* __restrict__ beta5,
                                               float* __restrict__ out, int N) {
  int gid = blockIdx.x * 256 + threadIdx.x;
  int y = gid >> 6, u = gid & 63;
  if (y >= N) return;
  int var = (y == 0) ? 0 : (y == 1) ? 1 : (y == N - 2) ? 3 : (y == N - 1) ? 4 : 2;
  float acc = beta5[var * 64 + u];
#pragma unroll
  for (int d = 0; d < 7; ++d) {
    int yy = y + d - 3;
    if ((unsigned)yy >= (unsigned)N) continue;
    const float* hr = h + (size_t)yy * 64;
    const float* mr = M5 + ((var * 7 + d) * 64 + u) * 7;
#pragma unroll
    for (int jw = 0; jw < 7; ++jw) {
      int w = u + jw - 3;
      if ((unsigned)w < 64u) acc += mr[jw] * hr[w];
    }
  }
  out[(size_t)y * 64 + u] = acc;
}

// ------------------------------- launcher -----------------------------------
extern "C" void kernel_launch(void* const* d_in, const int* in_sizes, int n_in,
                              void* d_out, int out_size, void* d_ws, size_t ws_size,
                              hipStream_t stream) {
  const int N = NN, E = NE;
  const float* x   = (const float*)d_in[0];
  const int*   ei  = (const int*)d_in[1];
  const float* Wl1 = (const float*)d_in[2];
  const float* bl1 = (const float*)d_in[3];
  const float* Wr1 = (const float*)d_in[4];
  const float* Wl2 = (const float*)d_in[5];
  const float* bl2 = (const float*)d_in[6];
  const float* Wr2 = (const float*)d_in[7];
  const float* Wl3 = (const float*)d_in[8];
  const float* bl3 = (const float*)d_in[9];
  const float* Wr3 = (const float*)d_in[10];
  const float* Wc1 = (const float*)d_in[11];
  const float* bc1 = (const float*)d_in[12];
  const float* Wc2 = (const float*)d_in[13];
  const float* bc2 = (const float*)d_in[14];
  const float* Wc3 = (const float*)d_in[15];
  const float* bc3 = (const float*)d_in[16];
  const float* W2  = (const float*)d_in[17];
  const float* b2  = (const float*)d_in[18];

  char* ws = (char*)d_ws;
  size_t off = 0;
  auto alloc = [&](size_t bytes) -> void* {
    off = (off + 255) & ~(size_t)255;
    void* p = ws + off;
    off += bytes;
    return p;
  };
  int*   eflag  = (int*)alloc(4);
  int*   rowptr = (int*)alloc((size_t)(N + 1) * 4);
  int*   cursor = (int*)alloc((size_t)N * 4);
  float* invdeg = (float*)alloc((size_t)N * 4);
  int*   csr    = (int*)alloc((size_t)E * 4);
  float* Wt1    = (float*)alloc(128 * 128 * 4);
  float* Wt2    = (float*)alloc(64 * 128 * 4);
  float* Wt3    = (float*)alloc(64 * 64 * 4);
  float* W2t    = (float*)alloc(64 * 64 * 4);
  float* CBp    = (float*)alloc(184320 * 4);
  float* M5     = (float*)alloc(15680 * 4);
  float* beta5  = (float*)alloc(320 * 4);
  float* yz     = (float*)alloc((size_t)N * 128 * 4);  // also reused as conv out
  float* hA     = (float*)alloc((size_t)N * 64 * 4);
  float* hB     = (float*)alloc((size_t)N * 64 * 4);
  (void)ws_size; (void)in_sizes; (void)n_in; (void)out_size;

  const int gE = (E + 255) / 256;       // 2500
  const int gG = (N + 63) / 64;         // 313
  const int gA = (N + 3) / 4;           // 5000
  const int gP = (N * 64 + 255) / 256;  // 5000

  // CSR build (once; shared by all 6 sage layers)
  k_probe<<<1, 64, 0, stream>>>(ei, eflag);
  hipMemsetAsync(cursor, 0, (size_t)N * 4, stream);
  k_hist<<<gE, 256, 0, stream>>>(ei, eflag, cursor, E);
  k_scan<<<1, 1024, 0, stream>>>(cursor, rowptr, invdeg, N, E);
  k_scatter<<<gE, 256, 0, stream>>>(ei, eflag, cursor, csr, E);

  // weight transposes
  k_wtrans<<<(128 * 128 + 255) / 256, 256, 0, stream>>>(Wl1, Wr1, Wt1, 64, 128);
  k_wtrans<<<(64 * 128 + 255) / 256, 256, 0, stream>>>(Wl2, Wr2, Wt2, 64, 64);
  k_wtrans<<<(64 * 64 + 255) / 256, 256, 0, stream>>>(Wl3, Wr3, Wt3, 32, 64);
  k_wtrans<<<(64 * 64 + 255) / 256, 256, 0, stream>>>(W2, nullptr, W2t, 64, 64);

  // conv composite operator build
  k_cbp<<<720, 256, 0, stream>>>(Wc2, Wc3, CBp);
  k_m5<<<62, 256, 0, stream>>>(CBp, Wc1, M5);
  k_beta<<<5, 256, 0, stream>>>(Wc2, Wc3, bc1, bc2, bc3, beta5);

  // sage1: x[ N x128 ] -> yz (y|z), agg -> hA
  k_gemm<128, 128><<<gG, 256, 0, stream>>>(x, Wt1, nullptr, yz, N);
  k_agg<<<gA, 256, 0, stream>>>(yz, csr, rowptr, invdeg, bl1, hA, N, 64);
  // sage2: hA -> hB
  k_gemm<128, 64><<<gG, 256, 0, stream>>>(hA, Wt2, nullptr, yz, N);
  k_agg<<<gA, 256, 0, stream>>>(yz, csr, rowptr, invdeg, bl2, hB, N, 64);
  // sage3: hB -> hA
  k_gemm<128, 64><<<gG, 256, 0, stream>>>(hB, Wt2, nullptr, yz, N);
  k_agg<<<gA, 256, 0, stream>>>(yz, csr, rowptr, invdeg, bl2, hA, N, 64);

  // conv stack + residual (composite banded operator), into yz (reused)
  k_apply<<<gP, 256, 0, stream>>>(hA, M5, beta5, yz, N);
  // linear2: yz -> hB
  k_gemm<64, 64><<<gG, 256, 0, stream>>>(yz, W2t, b2, hB, N);

  // sage4: hB -> hA
  k_gemm<128, 64><<<gG, 256, 0, stream>>>(hB, Wt2, nullptr, yz, N);
  k_agg<<<gA, 256, 0, stream>>>(yz, csr, rowptr, invdeg, bl2, hA, N, 64);
  // sage5: hA -> hB
  k_gemm<128, 64><<<gG, 256, 0, stream>>>(hA, Wt2, nullptr, yz, N);
  k_agg<<<gA, 256, 0, stream>>>(yz, csr, rowptr, invdeg, bl2, hB, N, 64);
  // sage6: hB -> d_out (32-dim)
  k_gemm<64, 64><<<gG, 256, 0, stream>>>(hB, Wt3, nullptr, yz, N);
  k_agg<<<gA, 256, 0, stream>>>(yz, csr, rowptr, invdeg, bl3, (float*)d_out, N, 32);
}

// Round 4
// 641.332 us; speedup vs baseline: 1.6841x; 1.0981x over previous
//
#include <hip/hip_runtime.h>

#define NN 20000
#define NE 640000

// ---------------------- edge-index dtype probe ------------------------------
__global__ void k_probe(const int* __restrict__ ei32, int* __restrict__ flag) {
  int lane = threadIdx.x & 63;
  int v = ei32[2 * lane + 1];
  unsigned long long nz = __ballot(v != 0);
  if (lane == 0) *flag = (nz == 0ull) ? 2 : 1;  // words per logical element
}

// ----------------------------- CSR build -----------------------------------
__global__ __launch_bounds__(256) void k_hist(const int* __restrict__ ei,
                                              const int* __restrict__ flag,
                                              int* __restrict__ cnt, int E) {
  int st = *flag;
  int e = blockIdx.x * 256 + threadIdx.x;
  if (e < E) atomicAdd(&cnt[ei[(size_t)(E + e) * st]], 1);
}

__global__ __launch_bounds__(1024) void k_scan(int* __restrict__ cur,
                                               int* __restrict__ rowptr,
                                               float* __restrict__ invdeg,
                                               int N, int E) {
  __shared__ int lds[1024];
  int tid = threadIdx.x;
  const int CH = (N + 1023) / 1024;
  int base = tid * CH;
  int s = 0;
  for (int c = 0; c < CH; ++c) { int i = base + c; if (i < N) s += cur[i]; }
  lds[tid] = s;
  __syncthreads();
  for (int off = 1; off < 1024; off <<= 1) {
    int v = (tid >= off) ? lds[tid - off] : 0;
    __syncthreads();
    lds[tid] += v;
    __syncthreads();
  }
  int run = (tid == 0) ? 0 : lds[tid - 1];
  for (int c = 0; c < CH; ++c) {
    int i = base + c; if (i >= N) break;
    int dg = cur[i];
    rowptr[i] = run;
    cur[i] = run;                       // cursor for scatter
    invdeg[i] = 1.0f / (float)(dg < 1 ? 1 : dg);
    run += dg;
  }
  if (tid == 0) rowptr[N] = E;
}

__global__ __launch_bounds__(256) void k_scatter(const int* __restrict__ ei,
                                                 const int* __restrict__ flag,
                                                 int* __restrict__ cur,
                                                 int* __restrict__ csr, int E) {
  int st = *flag;
  int e = blockIdx.x * 256 + threadIdx.x;
  if (e < E) {
    int d = ei[(size_t)(E + e) * st];
    int p = atomicAdd(&cur[d], 1);
    csr[p] = ei[(size_t)e * st];
  }
}

// ------------------------ weight transpose (concat) -------------------------
__global__ __launch_bounds__(256) void k_wtrans(const float* __restrict__ A,
                                                const float* __restrict__ B,
                                                float* __restrict__ out,
                                                int dh, int K) {
  int C = B ? 2 * dh : dh;
  int total = K * C;
  int idx = blockIdx.x * 256 + threadIdx.x;
  if (idx >= total) return;
  int w = idx / C, u = idx - w * C;
  out[idx] = (u < dh) ? A[u * K + w] : B[(u - dh) * K + w];
}

// ------------------- conv composite operator build --------------------------
// Stage 1: S9[a][b] = sum_o Wc3[o*9+a] * Wc2[o*576+b]
//   a = d2*3 + (dl2+1)   (conv3 vertical tap x horizontal offset)
//   b = i*9 + d1*3 + (dl1+1)
// One block of 576 threads; Wc2 reads fully coalesced; Wc3 in LDS.
__global__ __launch_bounds__(576) void k_s9(const float* __restrict__ Wc2,
                                            const float* __restrict__ Wc3,
                                            float* __restrict__ S9) {
  __shared__ float W3[576];
  int b = threadIdx.x;
  W3[b] = Wc3[b];
  __syncthreads();
  float acc[9];
#pragma unroll
  for (int a = 0; a < 9; ++a) acc[a] = 0.0f;
#pragma unroll 4
  for (int o = 0; o < 64; ++o) {
    float w2 = Wc2[o * 576 + b];
#pragma unroll
    for (int a = 0; a < 9; ++a) acc[a] += W3[o * 9 + a] * w2;
  }
#pragma unroll
  for (int a = 0; a < 9; ++a) S9[a * 576 + b] = acc[a];
}

// Stage 2: T729[c] = sum_i S9[a(c)*576 + i*9 + bcol(c)] * Wc1[i*9 + ky0*3 + kx0]
//   c = ((ky2*3+ky1)*3+ky0)*27 + dl2e*9 + dl1e*3 + kx0
// One block; everything in LDS.
__global__ __launch_bounds__(256) void k_t729(const float* __restrict__ S9,
                                              const float* __restrict__ Wc1,
                                              float* __restrict__ T729) {
  __shared__ float S9s[5184];
  __shared__ float W1s[576];
  int tid = threadIdx.x;
  for (int e = tid; e < 5184; e += 256) S9s[e] = S9[e];
  for (int e = tid; e < 576; e += 256) W1s[e] = Wc1[e];
  __syncthreads();
  for (int c = tid; c < 729; c += 256) {
    int kx0  = c % 3;
    int dl1e = (c / 3) % 3;
    int dl2e = (c / 9) % 3;
    int ky0  = (c / 27) % 3;
    int ky1  = (c / 81) % 3;
    int ky2  = c / 243;
    const float* s9 = &S9s[(ky2 * 3 + dl2e) * 576 + ky1 * 3 + dl1e];
    const float* w1 = &W1s[ky0 * 3 + kx0];
    float t = 0.0f;
#pragma unroll 8
    for (int i = 0; i < 64; ++i) t += s9[i * 9] * w1[i * 9];
    T729[c] = t;
  }
}

__device__ __forceinline__ bool maskB(int var, int o2, int o1) {
  int s = o2 + o1;
  switch (var) {
    case 0: return (o2 >= 0) && (s >= 0);
    case 1: return s >= -1;
    case 3: return s <= 1;
    case 4: return (o2 <= 0) && (s <= 0);
    default: return true;
  }
}

// Stage 3: M5[var][d][u][jw] = masked sum over T729 entries (LDS table).
// kx0 = jw-jq; dl1e = jq-dl2e. Residual identity at d=3,jw=3.
__global__ __launch_bounds__(256) void k_m5(const float* __restrict__ T729,
                                            float* __restrict__ M5) {
  __shared__ float Ts[729];
  int tid = threadIdx.x;
  for (int e = tid; e < 729; e += 256) Ts[e] = T729[e];
  __syncthreads();
  int idx = blockIdx.x * 256 + tid;
  if (idx >= 15680) return;
  int jw = idx % 7;
  int u  = (idx / 7) % 64;
  int d  = (idx / 448) % 7;
  int var = idx / 3136;
  int w = u + jw - 3;
  float s = 0.0f;
  if (w >= 0 && w < 64) {
    for (int ky2 = 0; ky2 < 3; ++ky2) {
      int o2 = ky2 - 1;
      for (int ky1 = 0; ky1 < 3; ++ky1) {
        int o1 = ky1 - 1;
        if (!maskB(var, o2, o1)) continue;
        int o0 = (d - 3) - o2 - o1;
        if (o0 < -1 || o0 > 1) continue;
        int ky0 = o0 + 1;
        int cbase = ((ky2 * 3 + ky1) * 3 + ky0) * 27;
#pragma unroll
        for (int kx0 = 0; kx0 < 3; ++kx0) {
          int jq = jw - kx0;
          if ((unsigned)jq >= 5u) continue;
          int q = u + jq - 2;
          if ((unsigned)q >= 64u) continue;
#pragma unroll
          for (int dl2e = 0; dl2e < 3; ++dl2e) {
            int p = u + dl2e - 1;
            if ((unsigned)p >= 64u) continue;
            int dl1e = jq - dl2e;
            if ((unsigned)dl1e >= 3u) continue;
            s += Ts[cbase + dl2e * 9 + dl1e * 3 + kx0];
          }
        }
      }
    }
  }
  if (d == 3 && jw == 3) s += 1.0f;  // residual: out = conv(h) + h (ONLY here)
  M5[idx] = s;
}

// beta5[var][u]: bias propagation through the conv stack (with truncations).
__global__ __launch_bounds__(256) void k_beta(const float* __restrict__ Wc2,
                                              const float* __restrict__ Wc3,
                                              const float* __restrict__ bc1,
                                              const float* __restrict__ bc2,
                                              const float* __restrict__ bc3,
                                              float* __restrict__ beta5) {
  __shared__ float S2[576];  // S2[o][ky][kx] = sum_i Wc2[o,i,ky,kx]*bc1[i]
  __shared__ float W3[576];
  __shared__ float B2[64];
  __shared__ float part[256];
  int tid = threadIdx.x;
  int var = blockIdx.x;
  for (int e = tid; e < 576; e += 256) {
    int o = e / 9, r = e - o * 9;
    float t = 0.0f;
    for (int i = 0; i < 64; ++i) t += Wc2[o * 576 + i * 9 + r] * bc1[i];
    S2[e] = t;
    W3[e] = Wc3[e];
  }
  if (tid < 64) B2[tid] = bc2[tid];
  __syncthreads();
  int u = tid & 63, oc = tid >> 6;
  float s = 0.0f;
  for (int ky2 = 0; ky2 < 3; ++ky2) {
    int o2 = ky2 - 1;
    bool okA = (var == 0) ? (o2 >= 0) : (var == 4) ? (o2 <= 0) : true;
    if (!okA) continue;
    for (int dl2 = -1; dl2 <= 1; ++dl2) {
      int p = u + dl2; if ((unsigned)p >= 64u) continue;
      float sel[9];
#pragma unroll
      for (int ky1 = 0; ky1 < 3; ++ky1) {
        int o1 = ky1 - 1;
        bool mb = maskB(var, o2, o1);
#pragma unroll
        for (int dl1 = -1; dl1 <= 1; ++dl1) {
          int pq = p + dl1;
          sel[ky1 * 3 + dl1 + 1] = (mb && (unsigned)pq < 64u) ? 1.0f : 0.0f;
        }
      }
#pragma unroll 4
      for (int oo = 0; oo < 16; ++oo) {
        int o = oc * 16 + oo;
        float inner = B2[o];
#pragma unroll
        for (int r = 0; r < 9; ++r) inner += S2[o * 9 + r] * sel[r];
        s += W3[o * 9 + ky2 * 3 + (dl2 + 1)] * inner;
      }
    }
  }
  part[tid] = s;
  __syncthreads();
  if (tid < 64) {
    beta5[var * 64 + tid] =
        bc3[0] + part[tid] + part[64 + tid] + part[128 + tid] + part[192 + tid];
  }
}

// ----------------------------- dense GEMM -----------------------------------
template <int C, int K>
__global__ __launch_bounds__(256) void k_gemm(const float* __restrict__ X,
                                              const float* __restrict__ Wt,
                                              const float* __restrict__ bias,
                                              float* __restrict__ out, int N) {
  constexpr int RPT = (C * 64) / 256;  // rows per thread
  __shared__ float Xs[64 * K];
  int y0 = blockIdx.x * 64;
  for (int idx = threadIdx.x; idx < 64 * K; idx += 256) {
    int r = idx / K, w = idx - r * K;
    int y = y0 + r;
    Xs[idx] = (y < N) ? X[(size_t)y * K + w] : 0.0f;
  }
  __syncthreads();
  int u = threadIdx.x % C;
  int rg = threadIdx.x / C;
  float acc[RPT];
  float bv = bias ? bias[u] : 0.0f;
#pragma unroll
  for (int k = 0; k < RPT; ++k) acc[k] = bv;
  for (int w0 = 0; w0 < K; w0 += 4) {
    float m0 = Wt[(w0 + 0) * C + u];
    float m1 = Wt[(w0 + 1) * C + u];
    float m2 = Wt[(w0 + 2) * C + u];
    float m3 = Wt[(w0 + 3) * C + u];
    const float* xs = &Xs[(rg * RPT) * K + w0];
#pragma unroll
    for (int k = 0; k < RPT; ++k) {
      float4 h = *(const float4*)(xs + k * K);
      acc[k] += m0 * h.x + m1 * h.y + m2 * h.z + m3 * h.w;
    }
  }
#pragma unroll
  for (int k = 0; k < RPT; ++k) {
    int y = y0 + rg * RPT + k;
    if (y < N) out[(size_t)y * C + u] = acc[k];
  }
}

// --------------------------- mean aggregation -------------------------------
__global__ __launch_bounds__(256) void k_agg(const float* __restrict__ yz,
                                             const int* __restrict__ csr,
                                             const int* __restrict__ rowptr,
                                             const float* __restrict__ invdeg,
                                             const float* __restrict__ bl,
                                             float* __restrict__ out,
                                             int N, int dh) {
  int node = blockIdx.x * 4 + (threadIdx.x >> 6);
  int lane = threadIdx.x & 63;
  if (node >= N) return;
  int S = 2 * dh;
  int beg = rowptr[node], end = rowptr[node + 1];
  if (lane < dh) {
    float acc = 0.0f;
    int j = beg;
    for (; j + 3 < end; j += 4) {
      int s0 = csr[j], s1 = csr[j + 1], s2 = csr[j + 2], s3 = csr[j + 3];
      float a0 = yz[(size_t)s0 * S + lane];
      float a1 = yz[(size_t)s1 * S + lane];
      float a2 = yz[(size_t)s2 * S + lane];
      float a3 = yz[(size_t)s3 * S + lane];
      acc += a0 + a1 + a2 + a3;
    }
    for (; j < end; ++j) acc += yz[(size_t)csr[j] * S + lane];
    out[(size_t)node * dh + lane] =
        acc * invdeg[node] + bl[lane] + yz[(size_t)node * S + dh + lane];
  }
}

// --------------------- conv composite apply (+residual) ---------------------
__global__ __launch_bounds__(256) void k_apply(const float* __restrict__ h,
                                               const float* __restrict__ M5,
                                               const float* __restrict__ beta5,
                                               float* __restrict__ out, int N) {
  int gid = blockIdx.x * 256 + threadIdx.x;
  int y = gid >> 6, u = gid & 63;
  if (y >= N) return;
  int var = (y == 0) ? 0 : (y == 1) ? 1 : (y == N - 2) ? 3 : (y == N - 1) ? 4 : 2;
  float acc = beta5[var * 64 + u];
#pragma unroll
  for (int d = 0; d < 7; ++d) {
    int yy = y + d - 3;
    if ((unsigned)yy >= (unsigned)N) continue;
    const float* hr = h + (size_t)yy * 64;
    const float* mr = M5 + ((var * 7 + d) * 64 + u) * 7;
#pragma unroll
    for (int jw = 0; jw < 7; ++jw) {
      int w = u + jw - 3;
      if ((unsigned)w < 64u) acc += mr[jw] * hr[w];
    }
  }
  out[(size_t)y * 64 + u] = acc;
}

// ------------------------------- launcher -----------------------------------
extern "C" void kernel_launch(void* const* d_in, const int* in_sizes, int n_in,
                              void* d_out, int out_size, void* d_ws, size_t ws_size,
                              hipStream_t stream) {
  const int N = NN, E = NE;
  const float* x   = (const float*)d_in[0];
  const int*   ei  = (const int*)d_in[1];
  const float* Wl1 = (const float*)d_in[2];
  const float* bl1 = (const float*)d_in[3];
  const float* Wr1 = (const float*)d_in[4];
  const float* Wl2 = (const float*)d_in[5];
  const float* bl2 = (const float*)d_in[6];
  const float* Wr2 = (const float*)d_in[7];
  const float* Wl3 = (const float*)d_in[8];
  const float* bl3 = (const float*)d_in[9];
  const float* Wr3 = (const float*)d_in[10];
  const float* Wc1 = (const float*)d_in[11];
  const float* bc1 = (const float*)d_in[12];
  const float* Wc2 = (const float*)d_in[13];
  const float* bc2 = (const float*)d_in[14];
  const float* Wc3 = (const float*)d_in[15];
  const float* bc3 = (const float*)d_in[16];
  const float* W2  = (const float*)d_in[17];
  const float* b2  = (const float*)d_in[18];

  char* ws = (char*)d_ws;
  size_t off = 0;
  auto alloc = [&](size_t bytes) -> void* {
    off = (off + 255) & ~(size_t)255;
    void* p = ws + off;
    off += bytes;
    return p;
  };
  int*   eflag  = (int*)alloc(4);
  int*   rowptr = (int*)alloc((size_t)(N + 1) * 4);
  int*   cursor = (int*)alloc((size_t)N * 4);
  float* invdeg = (float*)alloc((size_t)N * 4);
  int*   csr    = (int*)alloc((size_t)E * 4);
  float* Wt1    = (float*)alloc(128 * 128 * 4);
  float* Wt2    = (float*)alloc(64 * 128 * 4);
  float* Wt3    = (float*)alloc(64 * 64 * 4);
  float* W2t    = (float*)alloc(64 * 64 * 4);
  float* S9     = (float*)alloc(5184 * 4);
  float* T729   = (float*)alloc(729 * 4);
  float* M5     = (float*)alloc(15680 * 4);
  float* beta5  = (float*)alloc(320 * 4);
  float* yz     = (float*)alloc((size_t)N * 128 * 4);  // also reused as conv out
  float* hA     = (float*)alloc((size_t)N * 64 * 4);
  float* hB     = (float*)alloc((size_t)N * 64 * 4);
  (void)ws_size; (void)in_sizes; (void)n_in; (void)out_size;

  const int gE = (E + 255) / 256;       // 2500
  const int gG = (N + 63) / 64;         // 313
  const int gA = (N + 3) / 4;           // 5000
  const int gP = (N * 64 + 255) / 256;  // 5000

  // CSR build (once; shared by all 6 sage layers)
  k_probe<<<1, 64, 0, stream>>>(ei, eflag);
  hipMemsetAsync(cursor, 0, (size_t)N * 4, stream);
  k_hist<<<gE, 256, 0, stream>>>(ei, eflag, cursor, E);
  k_scan<<<1, 1024, 0, stream>>>(cursor, rowptr, invdeg, N, E);
  k_scatter<<<gE, 256, 0, stream>>>(ei, eflag, cursor, csr, E);

  // weight transposes
  k_wtrans<<<(128 * 128 + 255) / 256, 256, 0, stream>>>(Wl1, Wr1, Wt1, 64, 128);
  k_wtrans<<<(64 * 128 + 255) / 256, 256, 0, stream>>>(Wl2, Wr2, Wt2, 64, 64);
  k_wtrans<<<(64 * 64 + 255) / 256, 256, 0, stream>>>(Wl3, Wr3, Wt3, 32, 64);
  k_wtrans<<<(64 * 64 + 255) / 256, 256, 0, stream>>>(W2, nullptr, W2t, 64, 64);

  // conv composite operator build (3 tiny dense stages)
  k_s9<<<1, 576, 0, stream>>>(Wc2, Wc3, S9);
  k_t729<<<1, 256, 0, stream>>>(S9, Wc1, T729);
  k_m5<<<62, 256, 0, stream>>>(T729, M5);
  k_beta<<<5, 256, 0, stream>>>(Wc2, Wc3, bc1, bc2, bc3, beta5);

  // sage1: x[ N x128 ] -> yz (y|z), agg -> hA
  k_gemm<128, 128><<<gG, 256, 0, stream>>>(x, Wt1, nullptr, yz, N);
  k_agg<<<gA, 256, 0, stream>>>(yz, csr, rowptr, invdeg, bl1, hA, N, 64);
  // sage2: hA -> hB
  k_gemm<128, 64><<<gG, 256, 0, stream>>>(hA, Wt2, nullptr, yz, N);
  k_agg<<<gA, 256, 0, stream>>>(yz, csr, rowptr, invdeg, bl2, hB, N, 64);
  // sage3: hB -> hA
  k_gemm<128, 64><<<gG, 256, 0, stream>>>(hB, Wt2, nullptr, yz, N);
  k_agg<<<gA, 256, 0, stream>>>(yz, csr, rowptr, invdeg, bl2, hA, N, 64);

  // conv stack + residual (composite banded operator), into yz (reused)
  k_apply<<<gP, 256, 0, stream>>>(hA, M5, beta5, yz, N);
  // linear2: yz -> hB
  k_gemm<64, 64><<<gG, 256, 0, stream>>>(yz, W2t, b2, hB, N);

  // sage4: hB -> hA
  k_gemm<128, 64><<<gG, 256, 0, stream>>>(hB, Wt2, nullptr, yz, N);
  k_agg<<<gA, 256, 0, stream>>>(yz, csr, rowptr, invdeg, bl2, hA, N, 64);
  // sage5: hA -> hB
  k_gemm<128, 64><<<gG, 256, 0, stream>>>(hA, Wt2, nullptr, yz, N);
  k_agg<<<gA, 256, 0, stream>>>(yz, csr, rowptr, invdeg, bl2, hB, N, 64);
  // sage6: hB -> d_out (32-dim)
  k_gemm<64, 64><<<gG, 256, 0, stream>>>(hB, Wt3, nullptr, yz, N);
  k_agg<<<gA, 256, 0, stream>>>(yz, csr, rowptr, invdeg, bl3, (float*)d_out, N, 32);
}

// Round 5
// 555.839 us; speedup vs baseline: 1.9431x; 1.1538x over previous
//
#include <hip/hip_runtime.h>

#define NN 20000
#define NE 640000

// ---------------------- edge-index dtype probe ------------------------------
__global__ void k_probe(const int* __restrict__ ei32, int* __restrict__ flag) {
  int lane = threadIdx.x & 63;
  int v = ei32[2 * lane + 1];
  unsigned long long nz = __ballot(v != 0);
  if (lane == 0) *flag = (nz == 0ull) ? 2 : 1;  // words per logical element
}

// ----------------------------- CSR build -----------------------------------
__global__ __launch_bounds__(256) void k_hist(const int* __restrict__ ei,
                                              const int* __restrict__ flag,
                                              int* __restrict__ cnt, int E) {
  int st = *flag;
  int e = blockIdx.x * 256 + threadIdx.x;
  if (e < E) atomicAdd(&cnt[ei[(size_t)(E + e) * st]], 1);
}

__global__ __launch_bounds__(1024) void k_scan(int* __restrict__ cur,
                                               int* __restrict__ rowptr,
                                               float* __restrict__ invdeg,
                                               int N, int E) {
  __shared__ int lds[1024];
  int tid = threadIdx.x;
  const int CH = (N + 1023) / 1024;
  int base = tid * CH;
  int s = 0;
  for (int c = 0; c < CH; ++c) { int i = base + c; if (i < N) s += cur[i]; }
  lds[tid] = s;
  __syncthreads();
  for (int off = 1; off < 1024; off <<= 1) {
    int v = (tid >= off) ? lds[tid - off] : 0;
    __syncthreads();
    lds[tid] += v;
    __syncthreads();
  }
  int run = (tid == 0) ? 0 : lds[tid - 1];
  for (int c = 0; c < CH; ++c) {
    int i = base + c; if (i >= N) break;
    int dg = cur[i];
    rowptr[i] = run;
    cur[i] = run;                       // cursor for scatter
    invdeg[i] = 1.0f / (float)(dg < 1 ? 1 : dg);
    run += dg;
  }
  if (tid == 0) rowptr[N] = E;
}

__global__ __launch_bounds__(256) void k_scatter(const int* __restrict__ ei,
                                                 const int* __restrict__ flag,
                                                 int* __restrict__ cur,
                                                 int* __restrict__ csr, int E) {
  int st = *flag;
  int e = blockIdx.x * 256 + threadIdx.x;
  if (e < E) {
    int d = ei[(size_t)(E + e) * st];
    int p = atomicAdd(&cur[d], 1);
    csr[p] = ei[(size_t)e * st];
  }
}

// ------------------------ weight transpose (concat) -------------------------
__global__ __launch_bounds__(256) void k_wtrans(const float* __restrict__ A,
                                                const float* __restrict__ B,
                                                float* __restrict__ out,
                                                int dh, int K) {
  int C = B ? 2 * dh : dh;
  int total = K * C;
  int idx = blockIdx.x * 256 + threadIdx.x;
  if (idx >= total) return;
  int w = idx / C, u = idx - w * C;
  out[idx] = (u < dh) ? A[u * K + w] : B[(u - dh) * K + w];
}

// ------------------- conv composite operator build --------------------------
// Stage 1: S9[a][b] = sum_o Wc3[o*9+a] * Wc2[o*576+b]
__global__ __launch_bounds__(576) void k_s9(const float* __restrict__ Wc2,
                                            const float* __restrict__ Wc3,
                                            float* __restrict__ S9) {
  __shared__ float W3[576];
  int b = threadIdx.x;
  W3[b] = Wc3[b];
  __syncthreads();
  float acc[9];
#pragma unroll
  for (int a = 0; a < 9; ++a) acc[a] = 0.0f;
#pragma unroll 4
  for (int o = 0; o < 64; ++o) {
    float w2 = Wc2[o * 576 + b];
#pragma unroll
    for (int a = 0; a < 9; ++a) acc[a] += W3[o * 9 + a] * w2;
  }
#pragma unroll
  for (int a = 0; a < 9; ++a) S9[a * 576 + b] = acc[a];
}

// Stage 2: T729[c] = sum_i S9[a(c)*576 + i*9 + bcol(c)] * Wc1[i*9 + ky0*3 + kx0]
__global__ __launch_bounds__(256) void k_t729(const float* __restrict__ S9,
                                              const float* __restrict__ Wc1,
                                              float* __restrict__ T729) {
  __shared__ float S9s[5184];
  __shared__ float W1s[576];
  int tid = threadIdx.x;
  for (int e = tid; e < 5184; e += 256) S9s[e] = S9[e];
  for (int e = tid; e < 576; e += 256) W1s[e] = Wc1[e];
  __syncthreads();
  for (int c = tid; c < 729; c += 256) {
    int kx0  = c % 3;
    int dl1e = (c / 3) % 3;
    int dl2e = (c / 9) % 3;
    int ky0  = (c / 27) % 3;
    int ky1  = (c / 81) % 3;
    int ky2  = c / 243;
    const float* s9 = &S9s[(ky2 * 3 + dl2e) * 576 + ky1 * 3 + dl1e];
    const float* w1 = &W1s[ky0 * 3 + kx0];
    float t = 0.0f;
#pragma unroll 8
    for (int i = 0; i < 64; ++i) t += s9[i * 9] * w1[i * 9];
    T729[c] = t;
  }
}

__device__ __forceinline__ bool maskB(int var, int o2, int o1) {
  int s = o2 + o1;
  switch (var) {
    case 0: return (o2 >= 0) && (s >= 0);
    case 1: return s >= -1;
    case 3: return s <= 1;
    case 4: return (o2 <= 0) && (s <= 0);
    default: return true;
  }
}

// Stage 3: M5T[var][d][jw][u] = masked sum over T729 entries (LDS table).
// TRANSPOSED layout (u innermost) so k_apply coefficient loads coalesce.
__global__ __launch_bounds__(256) void k_m5(const float* __restrict__ T729,
                                            float* __restrict__ M5T) {
  __shared__ float Ts[729];
  int tid = threadIdx.x;
  for (int e = tid; e < 729; e += 256) Ts[e] = T729[e];
  __syncthreads();
  int idx = blockIdx.x * 256 + tid;
  if (idx >= 15680) return;
  int jw = idx % 7;
  int u  = (idx / 7) % 64;
  int d  = (idx / 448) % 7;
  int var = idx / 3136;
  int w = u + jw - 3;
  float s = 0.0f;
  if (w >= 0 && w < 64) {
    for (int ky2 = 0; ky2 < 3; ++ky2) {
      int o2 = ky2 - 1;
      for (int ky1 = 0; ky1 < 3; ++ky1) {
        int o1 = ky1 - 1;
        if (!maskB(var, o2, o1)) continue;
        int o0 = (d - 3) - o2 - o1;
        if (o0 < -1 || o0 > 1) continue;
        int ky0 = o0 + 1;
        int cbase = ((ky2 * 3 + ky1) * 3 + ky0) * 27;
#pragma unroll
        for (int kx0 = 0; kx0 < 3; ++kx0) {
          int jq = jw - kx0;
          if ((unsigned)jq >= 5u) continue;
          int q = u + jq - 2;
          if ((unsigned)q >= 64u) continue;
#pragma unroll
          for (int dl2e = 0; dl2e < 3; ++dl2e) {
            int p = u + dl2e - 1;
            if ((unsigned)p >= 64u) continue;
            int dl1e = jq - dl2e;
            if ((unsigned)dl1e >= 3u) continue;
            s += Ts[cbase + dl2e * 9 + dl1e * 3 + kx0];
          }
        }
      }
    }
  }
  if (d == 3 && jw == 3) s += 1.0f;  // residual: out = conv(h) + h (ONLY here)
  M5T[(var * 49 + d * 7 + jw) * 64 + u] = s;
}

// beta5[var][u]: bias propagation through the conv stack (with truncations).
__global__ __launch_bounds__(256) void k_beta(const float* __restrict__ Wc2,
                                              const float* __restrict__ Wc3,
                                              const float* __restrict__ bc1,
                                              const float* __restrict__ bc2,
                                              const float* __restrict__ bc3,
                                              float* __restrict__ beta5) {
  __shared__ float S2[576];
  __shared__ float W3[576];
  __shared__ float B2[64];
  __shared__ float part[256];
  int tid = threadIdx.x;
  int var = blockIdx.x;
  for (int e = tid; e < 576; e += 256) {
    int o = e / 9, r = e - o * 9;
    float t = 0.0f;
    for (int i = 0; i < 64; ++i) t += Wc2[o * 576 + i * 9 + r] * bc1[i];
    S2[e] = t;
    W3[e] = Wc3[e];
  }
  if (tid < 64) B2[tid] = bc2[tid];
  __syncthreads();
  int u = tid & 63, oc = tid >> 6;
  float s = 0.0f;
  for (int ky2 = 0; ky2 < 3; ++ky2) {
    int o2 = ky2 - 1;
    bool okA = (var == 0) ? (o2 >= 0) : (var == 4) ? (o2 <= 0) : true;
    if (!okA) continue;
    for (int dl2 = -1; dl2 <= 1; ++dl2) {
      int p = u + dl2; if ((unsigned)p >= 64u) continue;
      float sel[9];
#pragma unroll
      for (int ky1 = 0; ky1 < 3; ++ky1) {
        int o1 = ky1 - 1;
        bool mb = maskB(var, o2, o1);
#pragma unroll
        for (int dl1 = -1; dl1 <= 1; ++dl1) {
          int pq = p + dl1;
          sel[ky1 * 3 + dl1 + 1] = (mb && (unsigned)pq < 64u) ? 1.0f : 0.0f;
        }
      }
#pragma unroll 4
      for (int oo = 0; oo < 16; ++oo) {
        int o = oc * 16 + oo;
        float inner = B2[o];
#pragma unroll
        for (int r = 0; r < 9; ++r) inner += S2[o * 9 + r] * sel[r];
        s += W3[o * 9 + ky2 * 3 + (dl2 + 1)] * inner;
      }
    }
  }
  part[tid] = s;
  __syncthreads();
  if (tid < 64) {
    beta5[var * 64 + tid] =
        bc3[0] + part[tid] + part[64 + tid] + part[128 + tid] + part[192 + tid];
  }
}

// ----------------------------- dense GEMM -----------------------------------
template <int C, int K>
__global__ __launch_bounds__(256) void k_gemm(const float* __restrict__ X,
                                              const float* __restrict__ Wt,
                                              const float* __restrict__ bias,
                                              float* __restrict__ out, int N) {
  constexpr int RPT = (C * 64) / 256;  // rows per thread
  __shared__ float Xs[64 * K];
  int y0 = blockIdx.x * 64;
  for (int idx = threadIdx.x; idx < 64 * K; idx += 256) {
    int r = idx / K, w = idx - r * K;
    int y = y0 + r;
    Xs[idx] = (y < N) ? X[(size_t)y * K + w] : 0.0f;
  }
  __syncthreads();
  int u = threadIdx.x % C;
  int rg = threadIdx.x / C;
  float acc[RPT];
  float bv = bias ? bias[u] : 0.0f;
#pragma unroll
  for (int k = 0; k < RPT; ++k) acc[k] = bv;
  for (int w0 = 0; w0 < K; w0 += 4) {
    float m0 = Wt[(w0 + 0) * C + u];
    float m1 = Wt[(w0 + 1) * C + u];
    float m2 = Wt[(w0 + 2) * C + u];
    float m3 = Wt[(w0 + 3) * C + u];
    const float* xs = &Xs[(rg * RPT) * K + w0];
#pragma unroll
    for (int k = 0; k < RPT; ++k) {
      float4 h = *(const float4*)(xs + k * K);
      acc[k] += m0 * h.x + m1 * h.y + m2 * h.z + m3 * h.w;
    }
  }
#pragma unroll
  for (int k = 0; k < RPT; ++k) {
    int y = y0 + rg * RPT + k;
    if (y < N) out[(size_t)y * C + u] = acc[k];
  }
}

// --------------------------- mean aggregation -------------------------------
// Wave per node; lane = (edge subgroup g, feature quad f). Each wave-load
// fetches G=64/(DH/4) edge rows as float4 (256B/row coalesced). Cross-group
// reduction via shfl_xor. out[i] = invdeg*sum + bl + root(z).
template <int DH>
__global__ __launch_bounds__(256) void k_agg(const float* __restrict__ yz,
                                             const int* __restrict__ csr,
                                             const int* __restrict__ rowptr,
                                             const float* __restrict__ invdeg,
                                             const float* __restrict__ bl,
                                             float* __restrict__ out, int N) {
  constexpr int FV = DH / 4;   // lanes per edge row
  constexpr int G  = 64 / FV;  // edge rows per wave chunk
  constexpr int S4 = DH / 2;   // yz row stride in float4 (2*DH floats)
  int node = blockIdx.x * 4 + (threadIdx.x >> 6);
  int lane = threadIdx.x & 63;
  if (node >= N) return;
  int g = lane / FV, f = lane % FV;
  const float4* yz4 = (const float4*)yz;
  int beg = rowptr[node], end = rowptr[node + 1];
  float ax = 0.f, ay = 0.f, az = 0.f, aw = 0.f;
  float bx = 0.f, by = 0.f, bz = 0.f, bw = 0.f;
  int j = beg + g;
  for (; j + G < end; j += 2 * G) {
    int s0 = csr[j];
    int s1 = csr[j + G];
    float4 v0 = yz4[(size_t)s0 * S4 + f];
    float4 v1 = yz4[(size_t)s1 * S4 + f];
    ax += v0.x; ay += v0.y; az += v0.z; aw += v0.w;
    bx += v1.x; by += v1.y; bz += v1.z; bw += v1.w;
  }
  if (j < end) {
    int s0 = csr[j];
    float4 v0 = yz4[(size_t)s0 * S4 + f];
    ax += v0.x; ay += v0.y; az += v0.z; aw += v0.w;
  }
  ax += bx; ay += by; az += bz; aw += bw;
#pragma unroll
  for (int m = FV; m < 64; m <<= 1) {
    ax += __shfl_xor(ax, m, 64);
    ay += __shfl_xor(ay, m, 64);
    az += __shfl_xor(az, m, 64);
    aw += __shfl_xor(aw, m, 64);
  }
  if (g == 0) {
    float4 root = yz4[(size_t)node * S4 + FV + f];
    float4 bv = ((const float4*)bl)[f];
    float id = invdeg[node];
    float4 o;
    o.x = ax * id + bv.x + root.x;
    o.y = ay * id + bv.y + root.y;
    o.z = az * id + bv.z + root.z;
    o.w = aw * id + bv.w + root.w;
    ((float4*)out)[(size_t)node * FV + f] = o;
  }
}

// --------------------- conv composite apply (+residual) ---------------------
// Register-blocked banded stencil. Block = 32 output rows x 64 u; LDS tile
// hs[38][70] zero-padded. Thread = (u, 8-row strip); interior threads keep
// their 49 coefficients (var=2) in registers; sweep 14 input rows with 7 LDS
// reads each, compile-time-guarded FMA into acc[8].
__global__ __launch_bounds__(256) void k_apply(const float* __restrict__ h,
                                               const float* __restrict__ M5T,
                                               const float* __restrict__ beta5,
                                               float* __restrict__ out, int N) {
  __shared__ float hs[38 * 70];
  int tid = threadIdx.x;
  int bstart = blockIdx.x * 32;
  for (int idx = tid; idx < 38 * 70; idx += 256) {
    int row = idx / 70, col = idx - row * 70;
    int y = bstart - 3 + row;
    int w = col - 3;
    float v = 0.0f;
    if ((unsigned)y < (unsigned)N && (unsigned)w < 64u)
      v = h[(size_t)y * 64 + w];
    hs[idx] = v;
  }
  __syncthreads();
  int u = tid & 63, g = tid >> 6;
  int gstart = bstart + g * 8;
  const float* base = &hs[(g * 8) * 70 + u];
  bool interior = (gstart >= 2) && (gstart + 7 <= N - 3);
  if (interior) {
    float c[49];
#pragma unroll
    for (int t = 0; t < 49; ++t) c[t] = M5T[(2 * 49 + t) * 64 + u];
    float bet = beta5[2 * 64 + u];
    float acc[8];
#pragma unroll
    for (int k = 0; k < 8; ++k) acc[k] = bet;
#pragma unroll
    for (int rr = 0; rr < 14; ++rr) {
      float t7[7];
#pragma unroll
      for (int jw = 0; jw < 7; ++jw) t7[jw] = base[rr * 70 + jw];
#pragma unroll
      for (int d = 0; d < 7; ++d) {
        int k = rr - d;  // compile-time per unrolled (rr,d)
        if (k >= 0 && k < 8) {
#pragma unroll
          for (int jw = 0; jw < 7; ++jw) acc[k] += c[d * 7 + jw] * t7[jw];
        }
      }
    }
#pragma unroll
    for (int k = 0; k < 8; ++k) out[(size_t)(gstart + k) * 64 + u] = acc[k];
  } else {
    for (int k = 0; k < 8; ++k) {
      int y = gstart + k;
      if (y >= N) break;
      int var = (y == 0) ? 0 : (y == 1) ? 1 : (y == N - 2) ? 3 : (y == N - 1) ? 4 : 2;
      float acc = beta5[var * 64 + u];
      for (int d = 0; d < 7; ++d)
        for (int jw = 0; jw < 7; ++jw)
          acc += M5T[(var * 49 + d * 7 + jw) * 64 + u] * base[(k + d) * 70 + jw];
      out[(size_t)y * 64 + u] = acc;
    }
  }
}

// ------------------------------- launcher -----------------------------------
extern "C" void kernel_launch(void* const* d_in, const int* in_sizes, int n_in,
                              void* d_out, int out_size, void* d_ws, size_t ws_size,
                              hipStream_t stream) {
  const int N = NN, E = NE;
  const float* x   = (const float*)d_in[0];
  const int*   ei  = (const int*)d_in[1];
  const float* Wl1 = (const float*)d_in[2];
  const float* bl1 = (const float*)d_in[3];
  const float* Wr1 = (const float*)d_in[4];
  const float* Wl2 = (const float*)d_in[5];
  const float* bl2 = (const float*)d_in[6];
  const float* Wr2 = (const float*)d_in[7];
  const float* Wl3 = (const float*)d_in[8];
  const float* bl3 = (const float*)d_in[9];
  const float* Wr3 = (const float*)d_in[10];
  const float* Wc1 = (const float*)d_in[11];
  const float* bc1 = (const float*)d_in[12];
  const float* Wc2 = (const float*)d_in[13];
  const float* bc2 = (const float*)d_in[14];
  const float* Wc3 = (const float*)d_in[15];
  const float* bc3 = (const float*)d_in[16];
  const float* W2  = (const float*)d_in[17];
  const float* b2  = (const float*)d_in[18];

  char* ws = (char*)d_ws;
  size_t off = 0;
  auto alloc = [&](size_t bytes) -> void* {
    off = (off + 255) & ~(size_t)255;
    void* p = ws + off;
    off += bytes;
    return p;
  };
  int*   eflag  = (int*)alloc(4);
  int*   rowptr = (int*)alloc((size_t)(N + 1) * 4);
  int*   cursor = (int*)alloc((size_t)N * 4);
  float* invdeg = (float*)alloc((size_t)N * 4);
  int*   csr    = (int*)alloc((size_t)E * 4);
  float* Wt1    = (float*)alloc(128 * 128 * 4);
  float* Wt2    = (float*)alloc(64 * 128 * 4);
  float* Wt3    = (float*)alloc(64 * 64 * 4);
  float* W2t    = (float*)alloc(64 * 64 * 4);
  float* S9     = (float*)alloc(5184 * 4);
  float* T729   = (float*)alloc(729 * 4);
  float* M5T    = (float*)alloc(15680 * 4);
  float* beta5  = (float*)alloc(320 * 4);
  float* yz     = (float*)alloc((size_t)N * 128 * 4);  // also reused as conv out
  float* hA     = (float*)alloc((size_t)N * 64 * 4);
  float* hB     = (float*)alloc((size_t)N * 64 * 4);
  (void)ws_size; (void)in_sizes; (void)n_in; (void)out_size;

  const int gE = (E + 255) / 256;       // 2500
  const int gG = (N + 63) / 64;         // 313
  const int gA = (N + 3) / 4;           // 5000
  const int gP = N / 32;                // 625 (N divisible by 32)

  // CSR build (once; shared by all 6 sage layers)
  k_probe<<<1, 64, 0, stream>>>(ei, eflag);
  hipMemsetAsync(cursor, 0, (size_t)N * 4, stream);
  k_hist<<<gE, 256, 0, stream>>>(ei, eflag, cursor, E);
  k_scan<<<1, 1024, 0, stream>>>(cursor, rowptr, invdeg, N, E);
  k_scatter<<<gE, 256, 0, stream>>>(ei, eflag, cursor, csr, E);

  // weight transposes
  k_wtrans<<<(128 * 128 + 255) / 256, 256, 0, stream>>>(Wl1, Wr1, Wt1, 64, 128);
  k_wtrans<<<(64 * 128 + 255) / 256, 256, 0, stream>>>(Wl2, Wr2, Wt2, 64, 64);
  k_wtrans<<<(64 * 64 + 255) / 256, 256, 0, stream>>>(Wl3, Wr3, Wt3, 32, 64);
  k_wtrans<<<(64 * 64 + 255) / 256, 256, 0, stream>>>(W2, nullptr, W2t, 64, 64);

  // conv composite operator build (3 tiny dense stages)
  k_s9<<<1, 576, 0, stream>>>(Wc2, Wc3, S9);
  k_t729<<<1, 256, 0, stream>>>(S9, Wc1, T729);
  k_m5<<<62, 256, 0, stream>>>(T729, M5T);
  k_beta<<<5, 256, 0, stream>>>(Wc2, Wc3, bc1, bc2, bc3, beta5);

  // sage1: x[ N x128 ] -> yz (y|z), agg -> hA
  k_gemm<128, 128><<<gG, 256, 0, stream>>>(x, Wt1, nullptr, yz, N);
  k_agg<64><<<gA, 256, 0, stream>>>(yz, csr, rowptr, invdeg, bl1, hA, N);
  // sage2: hA -> hB
  k_gemm<128, 64><<<gG, 256, 0, stream>>>(hA, Wt2, nullptr, yz, N);
  k_agg<64><<<gA, 256, 0, stream>>>(yz, csr, rowptr, invdeg, bl2, hB, N);
  // sage3: hB -> hA
  k_gemm<128, 64><<<gG, 256, 0, stream>>>(hB, Wt2, nullptr, yz, N);
  k_agg<64><<<gA, 256, 0, stream>>>(yz, csr, rowptr, invdeg, bl2, hA, N);

  // conv stack + residual (composite banded operator), into yz (reused)
  k_apply<<<gP, 256, 0, stream>>>(hA, M5T, beta5, yz, N);
  // linear2: yz -> hB
  k_gemm<64, 64><<<gG, 256, 0, stream>>>(yz, W2t, b2, hB, N);

  // sage4: hB -> hA
  k_gemm<128, 64><<<gG, 256, 0, stream>>>(hB, Wt2, nullptr, yz, N);
  k_agg<64><<<gA, 256, 0, stream>>>(yz, csr, rowptr, invdeg, bl2, hA, N);
  // sage5: hA -> hB
  k_gemm<128, 64><<<gG, 256, 0, stream>>>(hA, Wt2, nullptr, yz, N);
  k_agg<64><<<gA, 256, 0, stream>>>(yz, csr, rowptr, invdeg, bl2, hB, N);
  // sage6: hB -> d_out (32-dim)
  k_gemm<64, 64><<<gG, 256, 0, stream>>>(hB, Wt3, nullptr, yz, N);
  k_agg<32><<<gA, 256, 0, stream>>>(yz, csr, rowptr, invdeg, bl3, (float*)d_out, N);
}

// Round 6
// 477.046 us; speedup vs baseline: 2.2640x; 1.1652x over previous
//
#include <hip/hip_runtime.h>

#define NN 20000
#define NE 640000

// ---------------------- edge-index dtype probe ------------------------------
__global__ void k_probe(const int* __restrict__ ei32, int* __restrict__ flag) {
  int lane = threadIdx.x & 63;
  int v = ei32[2 * lane + 1];
  unsigned long long nz = __ballot(v != 0);
  if (lane == 0) *flag = (nz == 0ull) ? 2 : 1;  // words per logical element
}

// ----------------------------- CSR build -----------------------------------
__global__ __launch_bounds__(256) void k_hist(const int* __restrict__ ei,
                                              const int* __restrict__ flag,
                                              int* __restrict__ cnt, int E) {
  int st = *flag;
  int e = blockIdx.x * 256 + threadIdx.x;
  if (e < E) atomicAdd(&cnt[ei[(size_t)(E + e) * st]], 1);
}

__global__ __launch_bounds__(1024) void k_scan(int* __restrict__ cur,
                                               int* __restrict__ rowptr,
                                               float* __restrict__ invdeg,
                                               int N, int E) {
  __shared__ int lds[1024];
  int tid = threadIdx.x;
  const int CH = (N + 1023) / 1024;
  int base = tid * CH;
  int s = 0;
  for (int c = 0; c < CH; ++c) { int i = base + c; if (i < N) s += cur[i]; }
  lds[tid] = s;
  __syncthreads();
  for (int off = 1; off < 1024; off <<= 1) {
    int v = (tid >= off) ? lds[tid - off] : 0;
    __syncthreads();
    lds[tid] += v;
    __syncthreads();
  }
  int run = (tid == 0) ? 0 : lds[tid - 1];
  for (int c = 0; c < CH; ++c) {
    int i = base + c; if (i >= N) break;
    int dg = cur[i];
    rowptr[i] = run;
    cur[i] = run;                       // cursor for scatter
    invdeg[i] = 1.0f / (float)(dg < 1 ? 1 : dg);
    run += dg;
  }
  if (tid == 0) rowptr[N] = E;
}

__global__ __launch_bounds__(256) void k_scatter(const int* __restrict__ ei,
                                                 const int* __restrict__ flag,
                                                 int* __restrict__ cur,
                                                 int* __restrict__ csr, int E) {
  int st = *flag;
  int e = blockIdx.x * 256 + threadIdx.x;
  if (e < E) {
    int d = ei[(size_t)(E + e) * st];
    int p = atomicAdd(&cur[d], 1);
    csr[p] = ei[(size_t)e * st];
  }
}

// ------------------------ weight transpose (concat) -------------------------
__global__ __launch_bounds__(256) void k_wtrans(const float* __restrict__ A,
                                                const float* __restrict__ B,
                                                float* __restrict__ out,
                                                int dh, int K) {
  int C = B ? 2 * dh : dh;
  int total = K * C;
  int idx = blockIdx.x * 256 + threadIdx.x;
  if (idx >= total) return;
  int w = idx / C, u = idx - w * C;
  out[idx] = (u < dh) ? A[u * K + w] : B[(u - dh) * K + w];
}

// ------------------- conv composite operator build --------------------------
// Stage 1: S9[a][b] = sum_o Wc3[o*9+a] * Wc2[o*576+b]
__global__ __launch_bounds__(576) void k_s9(const float* __restrict__ Wc2,
                                            const float* __restrict__ Wc3,
                                            float* __restrict__ S9) {
  __shared__ float W3[576];
  int b = threadIdx.x;
  W3[b] = Wc3[b];
  __syncthreads();
  float acc[9];
#pragma unroll
  for (int a = 0; a < 9; ++a) acc[a] = 0.0f;
#pragma unroll 4
  for (int o = 0; o < 64; ++o) {
    float w2 = Wc2[o * 576 + b];
#pragma unroll
    for (int a = 0; a < 9; ++a) acc[a] += W3[o * 9 + a] * w2;
  }
#pragma unroll
  for (int a = 0; a < 9; ++a) S9[a * 576 + b] = acc[a];
}

// Stage 2: T729[c] = sum_i S9[a(c)*576 + i*9 + bcol(c)] * Wc1[i*9 + ky0*3 + kx0]
__global__ __launch_bounds__(256) void k_t729(const float* __restrict__ S9,
                                              const float* __restrict__ Wc1,
                                              float* __restrict__ T729) {
  __shared__ float S9s[5184];
  __shared__ float W1s[576];
  int tid = threadIdx.x;
  for (int e = tid; e < 5184; e += 256) S9s[e] = S9[e];
  for (int e = tid; e < 576; e += 256) W1s[e] = Wc1[e];
  __syncthreads();
  for (int c = tid; c < 729; c += 256) {
    int kx0  = c % 3;
    int dl1e = (c / 3) % 3;
    int dl2e = (c / 9) % 3;
    int ky0  = (c / 27) % 3;
    int ky1  = (c / 81) % 3;
    int ky2  = c / 243;
    const float* s9 = &S9s[(ky2 * 3 + dl2e) * 576 + ky1 * 3 + dl1e];
    const float* w1 = &W1s[ky0 * 3 + kx0];
    float t = 0.0f;
#pragma unroll 8
    for (int i = 0; i < 64; ++i) t += s9[i * 9] * w1[i * 9];
    T729[c] = t;
  }
}

__device__ __forceinline__ bool maskB(int var, int o2, int o1) {
  int s = o2 + o1;
  switch (var) {
    case 0: return (o2 >= 0) && (s >= 0);
    case 1: return s >= -1;
    case 3: return s <= 1;
    case 4: return (o2 <= 0) && (s <= 0);
    default: return true;
  }
}

// Stage 3: M5T[var][d][jw][u] = masked sum over T729 entries (LDS table).
__global__ __launch_bounds__(256) void k_m5(const float* __restrict__ T729,
                                            float* __restrict__ M5T) {
  __shared__ float Ts[729];
  int tid = threadIdx.x;
  for (int e = tid; e < 729; e += 256) Ts[e] = T729[e];
  __syncthreads();
  int idx = blockIdx.x * 256 + tid;
  if (idx >= 15680) return;
  int jw = idx % 7;
  int u  = (idx / 7) % 64;
  int d  = (idx / 448) % 7;
  int var = idx / 3136;
  int w = u + jw - 3;
  float s = 0.0f;
  if (w >= 0 && w < 64) {
    for (int ky2 = 0; ky2 < 3; ++ky2) {
      int o2 = ky2 - 1;
      for (int ky1 = 0; ky1 < 3; ++ky1) {
        int o1 = ky1 - 1;
        if (!maskB(var, o2, o1)) continue;
        int o0 = (d - 3) - o2 - o1;
        if (o0 < -1 || o0 > 1) continue;
        int ky0 = o0 + 1;
        int cbase = ((ky2 * 3 + ky1) * 3 + ky0) * 27;
#pragma unroll
        for (int kx0 = 0; kx0 < 3; ++kx0) {
          int jq = jw - kx0;
          if ((unsigned)jq >= 5u) continue;
          int q = u + jq - 2;
          if ((unsigned)q >= 64u) continue;
#pragma unroll
          for (int dl2e = 0; dl2e < 3; ++dl2e) {
            int p = u + dl2e - 1;
            if ((unsigned)p >= 64u) continue;
            int dl1e = jq - dl2e;
            if ((unsigned)dl1e >= 3u) continue;
            s += Ts[cbase + dl2e * 9 + dl1e * 3 + kx0];
          }
        }
      }
    }
  }
  if (d == 3 && jw == 3) s += 1.0f;  // residual: out = conv(h) + h (ONLY here)
  M5T[(var * 49 + d * 7 + jw) * 64 + u] = s;
}

// beta5[var][u]: bias propagation through the conv stack (with truncations).
__global__ __launch_bounds__(256) void k_beta(const float* __restrict__ Wc2,
                                              const float* __restrict__ Wc3,
                                              const float* __restrict__ bc1,
                                              const float* __restrict__ bc2,
                                              const float* __restrict__ bc3,
                                              float* __restrict__ beta5) {
  __shared__ float S2[576];
  __shared__ float W3[576];
  __shared__ float B2[64];
  __shared__ float part[256];
  int tid = threadIdx.x;
  int var = blockIdx.x;
  for (int e = tid; e < 576; e += 256) {
    int o = e / 9, r = e - o * 9;
    float t = 0.0f;
    for (int i = 0; i < 64; ++i) t += Wc2[o * 576 + i * 9 + r] * bc1[i];
    S2[e] = t;
    W3[e] = Wc3[e];
  }
  if (tid < 64) B2[tid] = bc2[tid];
  __syncthreads();
  int u = tid & 63, oc = tid >> 6;
  float s = 0.0f;
  for (int ky2 = 0; ky2 < 3; ++ky2) {
    int o2 = ky2 - 1;
    bool okA = (var == 0) ? (o2 >= 0) : (var == 4) ? (o2 <= 0) : true;
    if (!okA) continue;
    for (int dl2 = -1; dl2 <= 1; ++dl2) {
      int p = u + dl2; if ((unsigned)p >= 64u) continue;
      float sel[9];
#pragma unroll
      for (int ky1 = 0; ky1 < 3; ++ky1) {
        int o1 = ky1 - 1;
        bool mb = maskB(var, o2, o1);
#pragma unroll
        for (int dl1 = -1; dl1 <= 1; ++dl1) {
          int pq = p + dl1;
          sel[ky1 * 3 + dl1 + 1] = (mb && (unsigned)pq < 64u) ? 1.0f : 0.0f;
        }
      }
#pragma unroll 4
      for (int oo = 0; oo < 16; ++oo) {
        int o = oc * 16 + oo;
        float inner = B2[o];
#pragma unroll
        for (int r = 0; r < 9; ++r) inner += S2[o * 9 + r] * sel[r];
        s += W3[o * 9 + ky2 * 3 + (dl2 + 1)] * inner;
      }
    }
  }
  part[tid] = s;
  __syncthreads();
  if (tid < 64) {
    beta5[var * 64 + tid] =
        bc3[0] + part[tid] + part[64 + tid] + part[128 + tid] + part[192 + tid];
  }
}

// ----------------------------- dense GEMM -----------------------------------
// out[N x C] = X[N x K] @ Wt[K x C] (+ bias). 16-row tile per block:
// N=20000 -> 1250 blocks (~5/CU) for latency hiding; RPT = 16*C/256 acc/thread.
template <int C, int K>
__global__ __launch_bounds__(256) void k_gemm(const float* __restrict__ X,
                                              const float* __restrict__ Wt,
                                              const float* __restrict__ bias,
                                              float* __restrict__ out, int N) {
  constexpr int ROWS = 16;                 // N % 16 == 0
  constexpr int RPT = ROWS * C / 256;      // C=128 -> 8, C=64 -> 4
  __shared__ float Xs[ROWS * K];
  int y0 = blockIdx.x * ROWS;
  {
    const float4* src = (const float4*)(X + (size_t)y0 * K);
    float4* dst = (float4*)Xs;
#pragma unroll
    for (int v = 0; v < ROWS * K / 4 / 256; ++v)
      dst[v * 256 + threadIdx.x] = src[v * 256 + threadIdx.x];
  }
  __syncthreads();
  int u = threadIdx.x % C;
  int rg = threadIdx.x / C;
  float acc[RPT];
  float bv = bias ? bias[u] : 0.0f;
#pragma unroll
  for (int k = 0; k < RPT; ++k) acc[k] = bv;
#pragma unroll 2
  for (int w0 = 0; w0 < K; w0 += 4) {
    float m0 = Wt[(w0 + 0) * C + u];
    float m1 = Wt[(w0 + 1) * C + u];
    float m2 = Wt[(w0 + 2) * C + u];
    float m3 = Wt[(w0 + 3) * C + u];
    const float* xs = &Xs[(rg * RPT) * K + w0];
#pragma unroll
    for (int k = 0; k < RPT; ++k) {
      float4 h = *(const float4*)(xs + k * K);
      acc[k] += m0 * h.x + m1 * h.y + m2 * h.z + m3 * h.w;
    }
  }
#pragma unroll
  for (int k = 0; k < RPT; ++k)
    out[(size_t)(y0 + rg * RPT + k) * C + u] = acc[k];
}

// --------------------------- mean aggregation -------------------------------
template <int DH>
__global__ __launch_bounds__(256) void k_agg(const float* __restrict__ yz,
                                             const int* __restrict__ csr,
                                             const int* __restrict__ rowptr,
                                             const float* __restrict__ invdeg,
                                             const float* __restrict__ bl,
                                             float* __restrict__ out, int N) {
  constexpr int FV = DH / 4;   // lanes per edge row
  constexpr int G  = 64 / FV;  // edge rows per wave chunk
  constexpr int S4 = DH / 2;   // yz row stride in float4 (2*DH floats)
  int node = blockIdx.x * 4 + (threadIdx.x >> 6);
  int lane = threadIdx.x & 63;
  if (node >= N) return;
  int g = lane / FV, f = lane % FV;
  const float4* yz4 = (const float4*)yz;
  int beg = rowptr[node], end = rowptr[node + 1];
  float ax = 0.f, ay = 0.f, az = 0.f, aw = 0.f;
  float bx = 0.f, by = 0.f, bz = 0.f, bw = 0.f;
  int j = beg + g;
  for (; j + G < end; j += 2 * G) {
    int s0 = csr[j];
    int s1 = csr[j + G];
    float4 v0 = yz4[(size_t)s0 * S4 + f];
    float4 v1 = yz4[(size_t)s1 * S4 + f];
    ax += v0.x; ay += v0.y; az += v0.z; aw += v0.w;
    bx += v1.x; by += v1.y; bz += v1.z; bw += v1.w;
  }
  if (j < end) {
    int s0 = csr[j];
    float4 v0 = yz4[(size_t)s0 * S4 + f];
    ax += v0.x; ay += v0.y; az += v0.z; aw += v0.w;
  }
  ax += bx; ay += by; az += bz; aw += bw;
#pragma unroll
  for (int m = FV; m < 64; m <<= 1) {
    ax += __shfl_xor(ax, m, 64);
    ay += __shfl_xor(ay, m, 64);
    az += __shfl_xor(az, m, 64);
    aw += __shfl_xor(aw, m, 64);
  }
  if (g == 0) {
    float4 root = yz4[(size_t)node * S4 + FV + f];
    float4 bv = ((const float4*)bl)[f];
    float id = invdeg[node];
    float4 o;
    o.x = ax * id + bv.x + root.x;
    o.y = ay * id + bv.y + root.y;
    o.z = az * id + bv.z + root.z;
    o.w = aw * id + bv.w + root.w;
    ((float4*)out)[(size_t)node * FV + f] = o;
  }
}

// --------------------- conv composite apply (+residual) ---------------------
__global__ __launch_bounds__(256) void k_apply(const float* __restrict__ h,
                                               const float* __restrict__ M5T,
                                               const float* __restrict__ beta5,
                                               float* __restrict__ out, int N) {
  __shared__ float hs[38 * 70];
  int tid = threadIdx.x;
  int bstart = blockIdx.x * 32;
  for (int idx = tid; idx < 38 * 70; idx += 256) {
    int row = idx / 70, col = idx - row * 70;
    int y = bstart - 3 + row;
    int w = col - 3;
    float v = 0.0f;
    if ((unsigned)y < (unsigned)N && (unsigned)w < 64u)
      v = h[(size_t)y * 64 + w];
    hs[idx] = v;
  }
  __syncthreads();
  int u = tid & 63, g = tid >> 6;
  int gstart = bstart + g * 8;
  const float* base = &hs[(g * 8) * 70 + u];
  bool interior = (gstart >= 2) && (gstart + 7 <= N - 3);
  if (interior) {
    float c[49];
#pragma unroll
    for (int t = 0; t < 49; ++t) c[t] = M5T[(2 * 49 + t) * 64 + u];
    float bet = beta5[2 * 64 + u];
    float acc[8];
#pragma unroll
    for (int k = 0; k < 8; ++k) acc[k] = bet;
#pragma unroll
    for (int rr = 0; rr < 14; ++rr) {
      float t7[7];
#pragma unroll
      for (int jw = 0; jw < 7; ++jw) t7[jw] = base[rr * 70 + jw];
#pragma unroll
      for (int d = 0; d < 7; ++d) {
        int k = rr - d;  // compile-time per unrolled (rr,d)
        if (k >= 0 && k < 8) {
#pragma unroll
          for (int jw = 0; jw < 7; ++jw) acc[k] += c[d * 7 + jw] * t7[jw];
        }
      }
    }
#pragma unroll
    for (int k = 0; k < 8; ++k) out[(size_t)(gstart + k) * 64 + u] = acc[k];
  } else {
    for (int k = 0; k < 8; ++k) {
      int y = gstart + k;
      if (y >= N) break;
      int var = (y == 0) ? 0 : (y == 1) ? 1 : (y == N - 2) ? 3 : (y == N - 1) ? 4 : 2;
      float acc = beta5[var * 64 + u];
      for (int d = 0; d < 7; ++d)
        for (int jw = 0; jw < 7; ++jw)
          acc += M5T[(var * 49 + d * 7 + jw) * 64 + u] * base[(k + d) * 70 + jw];
      out[(size_t)y * 64 + u] = acc;
    }
  }
}

// ------------------------------- launcher -----------------------------------
extern "C" void kernel_launch(void* const* d_in, const int* in_sizes, int n_in,
                              void* d_out, int out_size, void* d_ws, size_t ws_size,
                              hipStream_t stream) {
  const int N = NN, E = NE;
  const float* x   = (const float*)d_in[0];
  const int*   ei  = (const int*)d_in[1];
  const float* Wl1 = (const float*)d_in[2];
  const float* bl1 = (const float*)d_in[3];
  const float* Wr1 = (const float*)d_in[4];
  const float* Wl2 = (const float*)d_in[5];
  const float* bl2 = (const float*)d_in[6];
  const float* Wr2 = (const float*)d_in[7];
  const float* Wl3 = (const float*)d_in[8];
  const float* bl3 = (const float*)d_in[9];
  const float* Wr3 = (const float*)d_in[10];
  const float* Wc1 = (const float*)d_in[11];
  const float* bc1 = (const float*)d_in[12];
  const float* Wc2 = (const float*)d_in[13];
  const float* bc2 = (const float*)d_in[14];
  const float* Wc3 = (const float*)d_in[15];
  const float* bc3 = (const float*)d_in[16];
  const float* W2  = (const float*)d_in[17];
  const float* b2  = (const float*)d_in[18];

  char* ws = (char*)d_ws;
  size_t off = 0;
  auto alloc = [&](size_t bytes) -> void* {
    off = (off + 255) & ~(size_t)255;
    void* p = ws + off;
    off += bytes;
    return p;
  };
  int*   eflag  = (int*)alloc(4);
  int*   rowptr = (int*)alloc((size_t)(N + 1) * 4);
  int*   cursor = (int*)alloc((size_t)N * 4);
  float* invdeg = (float*)alloc((size_t)N * 4);
  int*   csr    = (int*)alloc((size_t)E * 4);
  float* Wt1    = (float*)alloc(128 * 128 * 4);
  float* Wt2    = (float*)alloc(64 * 128 * 4);
  float* Wt3    = (float*)alloc(64 * 64 * 4);
  float* W2t    = (float*)alloc(64 * 64 * 4);
  float* S9     = (float*)alloc(5184 * 4);
  float* T729   = (float*)alloc(729 * 4);
  float* M5T    = (float*)alloc(15680 * 4);
  float* beta5  = (float*)alloc(320 * 4);
  float* yz     = (float*)alloc((size_t)N * 128 * 4);  // also reused as conv out
  float* hA     = (float*)alloc((size_t)N * 64 * 4);
  float* hB     = (float*)alloc((size_t)N * 64 * 4);
  (void)ws_size; (void)in_sizes; (void)n_in; (void)out_size;

  const int gE = (E + 255) / 256;       // 2500
  const int gG = N / 16;                // 1250 (N divisible by 16)
  const int gA = (N + 3) / 4;           // 5000
  const int gP = N / 32;                // 625

  // CSR build (once; shared by all 6 sage layers)
  k_probe<<<1, 64, 0, stream>>>(ei, eflag);
  hipMemsetAsync(cursor, 0, (size_t)N * 4, stream);
  k_hist<<<gE, 256, 0, stream>>>(ei, eflag, cursor, E);
  k_scan<<<1, 1024, 0, stream>>>(cursor, rowptr, invdeg, N, E);
  k_scatter<<<gE, 256, 0, stream>>>(ei, eflag, cursor, csr, E);

  // weight transposes
  k_wtrans<<<(128 * 128 + 255) / 256, 256, 0, stream>>>(Wl1, Wr1, Wt1, 64, 128);
  k_wtrans<<<(64 * 128 + 255) / 256, 256, 0, stream>>>(Wl2, Wr2, Wt2, 64, 64);
  k_wtrans<<<(64 * 64 + 255) / 256, 256, 0, stream>>>(Wl3, Wr3, Wt3, 32, 64);
  k_wtrans<<<(64 * 64 + 255) / 256, 256, 0, stream>>>(W2, nullptr, W2t, 64, 64);

  // conv composite operator build (3 tiny dense stages)
  k_s9<<<1, 576, 0, stream>>>(Wc2, Wc3, S9);
  k_t729<<<1, 256, 0, stream>>>(S9, Wc1, T729);
  k_m5<<<62, 256, 0, stream>>>(T729, M5T);
  k_beta<<<5, 256, 0, stream>>>(Wc2, Wc3, bc1, bc2, bc3, beta5);

  // sage1: x[ N x128 ] -> yz (y|z), agg -> hA
  k_gemm<128, 128><<<gG, 256, 0, stream>>>(x, Wt1, nullptr, yz, N);
  k_agg<64><<<gA, 256, 0, stream>>>(yz, csr, rowptr, invdeg, bl1, hA, N);
  // sage2: hA -> hB
  k_gemm<128, 64><<<gG, 256, 0, stream>>>(hA, Wt2, nullptr, yz, N);
  k_agg<64><<<gA, 256, 0, stream>>>(yz, csr, rowptr, invdeg, bl2, hB, N);
  // sage3: hB -> hA
  k_gemm<128, 64><<<gG, 256, 0, stream>>>(hB, Wt2, nullptr, yz, N);
  k_agg<64><<<gA, 256, 0, stream>>>(yz, csr, rowptr, invdeg, bl2, hA, N);

  // conv stack + residual (composite banded operator), into yz (reused)
  k_apply<<<gP, 256, 0, stream>>>(hA, M5T, beta5, yz, N);
  // linear2: yz -> hB
  k_gemm<64, 64><<<gG, 256, 0, stream>>>(yz, W2t, b2, hB, N);

  // sage4: hB -> hA
  k_gemm<128, 64><<<gG, 256, 0, stream>>>(hB, Wt2, nullptr, yz, N);
  k_agg<64><<<gA, 256, 0, stream>>>(yz, csr, rowptr, invdeg, bl2, hA, N);
  // sage5: hA -> hB
  k_gemm<128, 64><<<gG, 256, 0, stream>>>(hA, Wt2, nullptr, yz, N);
  k_agg<64><<<gA, 256, 0, stream>>>(yz, csr, rowptr, invdeg, bl2, hB, N);
  // sage6: hB -> d_out (32-dim)
  k_gemm<64, 64><<<gG, 256, 0, stream>>>(hB, Wt3, nullptr, yz, N);
  k_agg<32><<<gA, 256, 0, stream>>>(yz, csr, rowptr, invdeg, bl3, (float*)d_out, N);
}

// Round 7
// 423.365 us; speedup vs baseline: 2.5511x; 1.1268x over previous
//
#include <hip/hip_runtime.h>

#define NN 20000
#define NE 640000

// ---------------------- edge-index dtype probe ------------------------------
__global__ void k_probe(const int* __restrict__ ei32, int* __restrict__ flag) {
  int lane = threadIdx.x & 63;
  int v = ei32[2 * lane + 1];
  unsigned long long nz = __ballot(v != 0);
  if (lane == 0) *flag = (nz == 0ull) ? 2 : 1;  // words per logical element
}

// ----------------------------- CSR build -----------------------------------
__global__ __launch_bounds__(256) void k_hist(const int* __restrict__ ei,
                                              const int* __restrict__ flag,
                                              int* __restrict__ cnt, int E) {
  int st = *flag;
  int e = blockIdx.x * 256 + threadIdx.x;
  if (e < E) atomicAdd(&cnt[ei[(size_t)(E + e) * st]], 1);
}

// Phase A: per-block sums of cnt
__global__ __launch_bounds__(256) void k_scanA(const int* __restrict__ cnt,
                                               int* __restrict__ partial, int N) {
  __shared__ int red[4];
  int i = blockIdx.x * 256 + threadIdx.x;
  int v = (i < N) ? cnt[i] : 0;
#pragma unroll
  for (int m = 1; m < 64; m <<= 1) v += __shfl_xor(v, m, 64);
  int wid = threadIdx.x >> 6, lane = threadIdx.x & 63;
  if (lane == 0) red[wid] = v;
  __syncthreads();
  if (threadIdx.x == 0)
    partial[blockIdx.x] = red[0] + red[1] + red[2] + red[3];
}

// Phase B: exclusive scan of NB (<128) partials; also writes rowptr[N]=E.
__global__ __launch_bounds__(128) void k_scanB(const int* __restrict__ partial,
                                               int* __restrict__ prefix,
                                               int* __restrict__ rowptr,
                                               int NB, int E, int N) {
  __shared__ int lds[128];
  int tid = threadIdx.x;
  int mine = (tid < NB) ? partial[tid] : 0;
  lds[tid] = mine;
  __syncthreads();
  for (int off = 1; off < 128; off <<= 1) {
    int v = (tid >= off) ? lds[tid - off] : 0;
    __syncthreads();
    lds[tid] += v;
    __syncthreads();
  }
  if (tid < NB) prefix[tid] = lds[tid] - mine;  // exclusive
  if (tid == 0) rowptr[N] = E;
}

// Phase C: block-local exclusive scan + prefix; write rowptr/cursor/invdeg.
__global__ __launch_bounds__(256) void k_scanC(const int* __restrict__ cnt,
                                               const int* __restrict__ prefix,
                                               int* __restrict__ rowptr,
                                               int* __restrict__ cursor,
                                               float* __restrict__ invdeg, int N) {
  __shared__ int wsum[4];
  int tid = threadIdx.x;
  int i = blockIdx.x * 256 + tid;
  int lane = tid & 63, wid = tid >> 6;
  int dg = (i < N) ? cnt[i] : 0;
  int s = dg;
#pragma unroll
  for (int off = 1; off < 64; off <<= 1) {
    int v = __shfl_up(s, off, 64);
    if (lane >= off) s += v;
  }
  if (lane == 63) wsum[wid] = s;
  __syncthreads();
  int woff = 0;
  for (int w = 0; w < wid; ++w) woff += wsum[w];
  int val = prefix[blockIdx.x] + woff + s - dg;
  if (i < N) {
    rowptr[i] = val;
    cursor[i] = val;
    invdeg[i] = 1.0f / (float)(dg < 1 ? 1 : dg);
  }
}

__global__ __launch_bounds__(256) void k_scatter(const int* __restrict__ ei,
                                                 const int* __restrict__ flag,
                                                 int* __restrict__ cur,
                                                 int* __restrict__ csr, int E) {
  int st = *flag;
  int e = blockIdx.x * 256 + threadIdx.x;
  if (e < E) {
    int d = ei[(size_t)(E + e) * st];
    int p = atomicAdd(&cur[d], 1);
    csr[p] = ei[(size_t)e * st];
  }
}

// ------------------------ weight transpose (concat) -------------------------
__global__ __launch_bounds__(256) void k_wtrans(const float* __restrict__ A,
                                                const float* __restrict__ B,
                                                float* __restrict__ out,
                                                int dh, int K) {
  int C = B ? 2 * dh : dh;
  int total = K * C;
  int idx = blockIdx.x * 256 + threadIdx.x;
  if (idx >= total) return;
  int w = idx / C, u = idx - w * C;
  out[idx] = (u < dh) ? A[u * K + w] : B[(u - dh) * K + w];
}

// ------------------- conv composite operator build --------------------------
__global__ __launch_bounds__(576) void k_s9(const float* __restrict__ Wc2,
                                            const float* __restrict__ Wc3,
                                            float* __restrict__ S9) {
  __shared__ float W3[576];
  int b = threadIdx.x;
  W3[b] = Wc3[b];
  __syncthreads();
  float acc[9];
#pragma unroll
  for (int a = 0; a < 9; ++a) acc[a] = 0.0f;
#pragma unroll 4
  for (int o = 0; o < 64; ++o) {
    float w2 = Wc2[o * 576 + b];
#pragma unroll
    for (int a = 0; a < 9; ++a) acc[a] += W3[o * 9 + a] * w2;
  }
#pragma unroll
  for (int a = 0; a < 9; ++a) S9[a * 576 + b] = acc[a];
}

__global__ __launch_bounds__(256) void k_t729(const float* __restrict__ S9,
                                              const float* __restrict__ Wc1,
                                              float* __restrict__ T729) {
  __shared__ float S9s[5184];
  __shared__ float W1s[576];
  int tid = threadIdx.x;
  for (int e = tid; e < 5184; e += 256) S9s[e] = S9[e];
  for (int e = tid; e < 576; e += 256) W1s[e] = Wc1[e];
  __syncthreads();
  for (int c = tid; c < 729; c += 256) {
    int kx0  = c % 3;
    int dl1e = (c / 3) % 3;
    int dl2e = (c / 9) % 3;
    int ky0  = (c / 27) % 3;
    int ky1  = (c / 81) % 3;
    int ky2  = c / 243;
    const float* s9 = &S9s[(ky2 * 3 + dl2e) * 576 + ky1 * 3 + dl1e];
    const float* w1 = &W1s[ky0 * 3 + kx0];
    float t = 0.0f;
#pragma unroll 8
    for (int i = 0; i < 64; ++i) t += s9[i * 9] * w1[i * 9];
    T729[c] = t;
  }
}

__device__ __forceinline__ bool maskB(int var, int o2, int o1) {
  int s = o2 + o1;
  switch (var) {
    case 0: return (o2 >= 0) && (s >= 0);
    case 1: return s >= -1;
    case 3: return s <= 1;
    case 4: return (o2 <= 0) && (s <= 0);
    default: return true;
  }
}

__global__ __launch_bounds__(256) void k_m5(const float* __restrict__ T729,
                                            float* __restrict__ M5T) {
  __shared__ float Ts[729];
  int tid = threadIdx.x;
  for (int e = tid; e < 729; e += 256) Ts[e] = T729[e];
  __syncthreads();
  int idx = blockIdx.x * 256 + tid;
  if (idx >= 15680) return;
  int jw = idx % 7;
  int u  = (idx / 7) % 64;
  int d  = (idx / 448) % 7;
  int var = idx / 3136;
  int w = u + jw - 3;
  float s = 0.0f;
  if (w >= 0 && w < 64) {
    for (int ky2 = 0; ky2 < 3; ++ky2) {
      int o2 = ky2 - 1;
      for (int ky1 = 0; ky1 < 3; ++ky1) {
        int o1 = ky1 - 1;
        if (!maskB(var, o2, o1)) continue;
        int o0 = (d - 3) - o2 - o1;
        if (o0 < -1 || o0 > 1) continue;
        int ky0 = o0 + 1;
        int cbase = ((ky2 * 3 + ky1) * 3 + ky0) * 27;
#pragma unroll
        for (int kx0 = 0; kx0 < 3; ++kx0) {
          int jq = jw - kx0;
          if ((unsigned)jq >= 5u) continue;
          int q = u + jq - 2;
          if ((unsigned)q >= 64u) continue;
#pragma unroll
          for (int dl2e = 0; dl2e < 3; ++dl2e) {
            int p = u + dl2e - 1;
            if ((unsigned)p >= 64u) continue;
            int dl1e = jq - dl2e;
            if ((unsigned)dl1e >= 3u) continue;
            s += Ts[cbase + dl2e * 9 + dl1e * 3 + kx0];
          }
        }
      }
    }
  }
  if (d == 3 && jw == 3) s += 1.0f;  // residual: out = conv(h) + h (ONLY here)
  M5T[(var * 49 + d * 7 + jw) * 64 + u] = s;
}

__global__ __launch_bounds__(256) void k_beta(const float* __restrict__ Wc2,
                                              const float* __restrict__ Wc3,
                                              const float* __restrict__ bc1,
                                              const float* __restrict__ bc2,
                                              const float* __restrict__ bc3,
                                              float* __restrict__ beta5) {
  __shared__ float S2[576];
  __shared__ float W3[576];
  __shared__ float B2[64];
  __shared__ float part[256];
  int tid = threadIdx.x;
  int var = blockIdx.x;
  for (int e = tid; e < 576; e += 256) {
    int o = e / 9, r = e - o * 9;
    float t = 0.0f;
    for (int i = 0; i < 64; ++i) t += Wc2[o * 576 + i * 9 + r] * bc1[i];
    S2[e] = t;
    W3[e] = Wc3[e];
  }
  if (tid < 64) B2[tid] = bc2[tid];
  __syncthreads();
  int u = tid & 63, oc = tid >> 6;
  float s = 0.0f;
  for (int ky2 = 0; ky2 < 3; ++ky2) {
    int o2 = ky2 - 1;
    bool okA = (var == 0) ? (o2 >= 0) : (var == 4) ? (o2 <= 0) : true;
    if (!okA) continue;
    for (int dl2 = -1; dl2 <= 1; ++dl2) {
      int p = u + dl2; if ((unsigned)p >= 64u) continue;
      float sel[9];
#pragma unroll
      for (int ky1 = 0; ky1 < 3; ++ky1) {
        int o1 = ky1 - 1;
        bool mb = maskB(var, o2, o1);
#pragma unroll
        for (int dl1 = -1; dl1 <= 1; ++dl1) {
          int pq = p + dl1;
          sel[ky1 * 3 + dl1 + 1] = (mb && (unsigned)pq < 64u) ? 1.0f : 0.0f;
        }
      }
#pragma unroll 4
      for (int oo = 0; oo < 16; ++oo) {
        int o = oc * 16 + oo;
        float inner = B2[o];
#pragma unroll
        for (int r = 0; r < 9; ++r) inner += S2[o * 9 + r] * sel[r];
        s += W3[o * 9 + ky2 * 3 + (dl2 + 1)] * inner;
      }
    }
  }
  part[tid] = s;
  __syncthreads();
  if (tid < 64) {
    beta5[var * 64 + tid] =
        bc3[0] + part[tid] + part[64 + tid] + part[128 + tid] + part[192 + tid];
  }
}

// ----------------------------- dense GEMM -----------------------------------
template <int C, int K>
__global__ __launch_bounds__(256) void k_gemm(const float* __restrict__ X,
                                              const float* __restrict__ Wt,
                                              const float* __restrict__ bias,
                                              float* __restrict__ out, int N) {
  constexpr int ROWS = 16;                 // N % 16 == 0
  constexpr int RPT = ROWS * C / 256;      // C=128 -> 8, C=64 -> 4
  __shared__ float Xs[ROWS * K];
  int y0 = blockIdx.x * ROWS;
  {
    const float4* src = (const float4*)(X + (size_t)y0 * K);
    float4* dst = (float4*)Xs;
#pragma unroll
    for (int v = 0; v < ROWS * K / 4 / 256; ++v)
      dst[v * 256 + threadIdx.x] = src[v * 256 + threadIdx.x];
  }
  __syncthreads();
  int u = threadIdx.x % C;
  int rg = threadIdx.x / C;
  float acc[RPT];
  float bv = bias ? bias[u] : 0.0f;
#pragma unroll
  for (int k = 0; k < RPT; ++k) acc[k] = bv;
#pragma unroll 2
  for (int w0 = 0; w0 < K; w0 += 4) {
    float m0 = Wt[(w0 + 0) * C + u];
    float m1 = Wt[(w0 + 1) * C + u];
    float m2 = Wt[(w0 + 2) * C + u];
    float m3 = Wt[(w0 + 3) * C + u];
    const float* xs = &Xs[(rg * RPT) * K + w0];
#pragma unroll
    for (int k = 0; k < RPT; ++k) {
      float4 h = *(const float4*)(xs + k * K);
      acc[k] += m0 * h.x + m1 * h.y + m2 * h.z + m3 * h.w;
    }
  }
#pragma unroll
  for (int k = 0; k < RPT; ++k)
    out[(size_t)(y0 + rg * RPT + k) * C + u] = acc[k];
}

// --------------------------- mean aggregation -------------------------------
// Wave per node. Phase 1: stage the node's CSR indices into LDS (coalesced).
// Phase 2: 4-deep unrolled gathers with LDS-resident indices (no index-load
// latency in the dependence chain). Overflow beyond CAP falls back to global.
template <int DH>
__global__ __launch_bounds__(256) void k_agg(const float* __restrict__ yz,
                                             const int* __restrict__ csr,
                                             const int* __restrict__ rowptr,
                                             const float* __restrict__ invdeg,
                                             const float* __restrict__ bl,
                                             float* __restrict__ out, int N) {
  constexpr int FV = DH / 4;   // lanes per edge row
  constexpr int G  = 64 / FV;  // edge rows per wave chunk
  constexpr int S4 = DH / 2;   // yz row stride in float4 (2*DH floats)
  constexpr int CAP = 256;     // staged indices per node (mean degree ~32)
  __shared__ int idxs[4 * CAP];
  int wid = threadIdx.x >> 6, lane = threadIdx.x & 63;
  int node = blockIdx.x * 4 + wid;  // N % 4 == 0, always valid
  int beg = rowptr[node], end = rowptr[node + 1];
  int cnt = end - beg;
  int m = cnt < CAP ? cnt : CAP;
  int* my = &idxs[wid * CAP];
  for (int k = lane; k < m; k += 64) my[k] = csr[beg + k];
  __syncthreads();
  int g = lane / FV, f = lane % FV;
  const float4* yz4 = (const float4*)yz;
  float a0x=0,a0y=0,a0z=0,a0w=0, a1x=0,a1y=0,a1z=0,a1w=0;
  float a2x=0,a2y=0,a2z=0,a2w=0, a3x=0,a3y=0,a3z=0,a3w=0;
  int j = g;
  for (; j + 3 * G < m; j += 4 * G) {
    int s0 = my[j], s1 = my[j + G], s2 = my[j + 2 * G], s3 = my[j + 3 * G];
    float4 v0 = yz4[(size_t)s0 * S4 + f];
    float4 v1 = yz4[(size_t)s1 * S4 + f];
    float4 v2 = yz4[(size_t)s2 * S4 + f];
    float4 v3 = yz4[(size_t)s3 * S4 + f];
    a0x += v0.x; a0y += v0.y; a0z += v0.z; a0w += v0.w;
    a1x += v1.x; a1y += v1.y; a1z += v1.z; a1w += v1.w;
    a2x += v2.x; a2y += v2.y; a2z += v2.z; a2w += v2.w;
    a3x += v3.x; a3y += v3.y; a3z += v3.z; a3w += v3.w;
  }
  for (; j < m; j += G) {
    int s0 = my[j];
    float4 v0 = yz4[(size_t)s0 * S4 + f];
    a0x += v0.x; a0y += v0.y; a0z += v0.z; a0w += v0.w;
  }
  for (int jj = beg + CAP + g; jj < end; jj += G) {
    int s0 = csr[jj];
    float4 v0 = yz4[(size_t)s0 * S4 + f];
    a0x += v0.x; a0y += v0.y; a0z += v0.z; a0w += v0.w;
  }
  float ax = (a0x + a1x) + (a2x + a3x);
  float ay = (a0y + a1y) + (a2y + a3y);
  float az = (a0z + a1z) + (a2z + a3z);
  float aw = (a0w + a1w) + (a2w + a3w);
#pragma unroll
  for (int mm = FV; mm < 64; mm <<= 1) {
    ax += __shfl_xor(ax, mm, 64);
    ay += __shfl_xor(ay, mm, 64);
    az += __shfl_xor(az, mm, 64);
    aw += __shfl_xor(aw, mm, 64);
  }
  if (g == 0) {
    float4 root = yz4[(size_t)node * S4 + FV + f];
    float4 bv = ((const float4*)bl)[f];
    float id = invdeg[node];
    float4 o;
    o.x = ax * id + bv.x + root.x;
    o.y = ay * id + bv.y + root.y;
    o.z = az * id + bv.z + root.z;
    o.w = aw * id + bv.w + root.w;
    ((float4*)out)[(size_t)node * FV + f] = o;
  }
}

// --------------------- conv composite apply (+residual) ---------------------
__global__ __launch_bounds__(256) void k_apply(const float* __restrict__ h,
                                               const float* __restrict__ M5T,
                                               const float* __restrict__ beta5,
                                               float* __restrict__ out, int N) {
  __shared__ float hs[38 * 70];
  int tid = threadIdx.x;
  int bstart = blockIdx.x * 32;
  for (int idx = tid; idx < 38 * 70; idx += 256) {
    int row = idx / 70, col = idx - row * 70;
    int y = bstart - 3 + row;
    int w = col - 3;
    float v = 0.0f;
    if ((unsigned)y < (unsigned)N && (unsigned)w < 64u)
      v = h[(size_t)y * 64 + w];
    hs[idx] = v;
  }
  __syncthreads();
  int u = tid & 63, g = tid >> 6;
  int gstart = bstart + g * 8;
  const float* base = &hs[(g * 8) * 70 + u];
  bool interior = (gstart >= 2) && (gstart + 7 <= N - 3);
  if (interior) {
    float c[49];
#pragma unroll
    for (int t = 0; t < 49; ++t) c[t] = M5T[(2 * 49 + t) * 64 + u];
    float bet = beta5[2 * 64 + u];
    float acc[8];
#pragma unroll
    for (int k = 0; k < 8; ++k) acc[k] = bet;
#pragma unroll
    for (int rr = 0; rr < 14; ++rr) {
      float t7[7];
#pragma unroll
      for (int jw = 0; jw < 7; ++jw) t7[jw] = base[rr * 70 + jw];
#pragma unroll
      for (int d = 0; d < 7; ++d) {
        int k = rr - d;  // compile-time per unrolled (rr,d)
        if (k >= 0 && k < 8) {
#pragma unroll
          for (int jw = 0; jw < 7; ++jw) acc[k] += c[d * 7 + jw] * t7[jw];
        }
      }
    }
#pragma unroll
    for (int k = 0; k < 8; ++k) out[(size_t)(gstart + k) * 64 + u] = acc[k];
  } else {
    for (int k = 0; k < 8; ++k) {
      int y = gstart + k;
      if (y >= N) break;
      int var = (y == 0) ? 0 : (y == 1) ? 1 : (y == N - 2) ? 3 : (y == N - 1) ? 4 : 2;
      float acc = beta5[var * 64 + u];
      for (int d = 0; d < 7; ++d)
        for (int jw = 0; jw < 7; ++jw)
          acc += M5T[(var * 49 + d * 7 + jw) * 64 + u] * base[(k + d) * 70 + jw];
      out[(size_t)y * 64 + u] = acc;
    }
  }
}

// ------------------------------- launcher -----------------------------------
extern "C" void kernel_launch(void* const* d_in, const int* in_sizes, int n_in,
                              void* d_out, int out_size, void* d_ws, size_t ws_size,
                              hipStream_t stream) {
  const int N = NN, E = NE;
  const float* x   = (const float*)d_in[0];
  const int*   ei  = (const int*)d_in[1];
  const float* Wl1 = (const float*)d_in[2];
  const float* bl1 = (const float*)d_in[3];
  const float* Wr1 = (const float*)d_in[4];
  const float* Wl2 = (const float*)d_in[5];
  const float* bl2 = (const float*)d_in[6];
  const float* Wr2 = (const float*)d_in[7];
  const float* Wl3 = (const float*)d_in[8];
  const float* bl3 = (const float*)d_in[9];
  const float* Wr3 = (const float*)d_in[10];
  const float* Wc1 = (const float*)d_in[11];
  const float* bc1 = (const float*)d_in[12];
  const float* Wc2 = (const float*)d_in[13];
  const float* bc2 = (const float*)d_in[14];
  const float* Wc3 = (const float*)d_in[15];
  const float* bc3 = (const float*)d_in[16];
  const float* W2  = (const float*)d_in[17];
  const float* b2  = (const float*)d_in[18];

  char* ws = (char*)d_ws;
  size_t off = 0;
  auto alloc = [&](size_t bytes) -> void* {
    off = (off + 255) & ~(size_t)255;
    void* p = ws + off;
    off += bytes;
    return p;
  };
  int*   eflag  = (int*)alloc(4);
  int*   rowptr = (int*)alloc((size_t)(N + 1) * 4);
  int*   cursor = (int*)alloc((size_t)N * 4);
  float* invdeg = (float*)alloc((size_t)N * 4);
  int*   csr    = (int*)alloc((size_t)E * 4);
  int*   partial= (int*)alloc(128 * 4);
  int*   prefix = (int*)alloc(128 * 4);
  float* Wt1    = (float*)alloc(128 * 128 * 4);
  float* Wt2    = (float*)alloc(64 * 128 * 4);
  float* Wt3    = (float*)alloc(64 * 64 * 4);
  float* W2t    = (float*)alloc(64 * 64 * 4);
  float* S9     = (float*)alloc(5184 * 4);
  float* T729   = (float*)alloc(729 * 4);
  float* M5T    = (float*)alloc(15680 * 4);
  float* beta5  = (float*)alloc(320 * 4);
  float* yz     = (float*)alloc((size_t)N * 128 * 4);  // also reused as conv out
  float* hA     = (float*)alloc((size_t)N * 64 * 4);
  float* hB     = (float*)alloc((size_t)N * 64 * 4);
  (void)ws_size; (void)in_sizes; (void)n_in; (void)out_size;

  const int gE = (E + 255) / 256;       // 2500
  const int gG = N / 16;                // 1250
  const int gA = N / 4;                 // 5000
  const int gP = N / 32;                // 625
  const int gS = (N + 255) / 256;       // 79

  // CSR build (once; shared by all 6 sage layers)
  k_probe<<<1, 64, 0, stream>>>(ei, eflag);
  hipMemsetAsync(cursor, 0, (size_t)N * 4, stream);
  k_hist<<<gE, 256, 0, stream>>>(ei, eflag, cursor, E);
  k_scanA<<<gS, 256, 0, stream>>>(cursor, partial, N);
  k_scanB<<<1, 128, 0, stream>>>(partial, prefix, rowptr, gS, E, N);
  k_scanC<<<gS, 256, 0, stream>>>(cursor, prefix, rowptr, cursor, invdeg, N);
  k_scatter<<<gE, 256, 0, stream>>>(ei, eflag, cursor, csr, E);

  // weight transposes
  k_wtrans<<<(128 * 128 + 255) / 256, 256, 0, stream>>>(Wl1, Wr1, Wt1, 64, 128);
  k_wtrans<<<(64 * 128 + 255) / 256, 256, 0, stream>>>(Wl2, Wr2, Wt2, 64, 64);
  k_wtrans<<<(64 * 64 + 255) / 256, 256, 0, stream>>>(Wl3, Wr3, Wt3, 32, 64);
  k_wtrans<<<(64 * 64 + 255) / 256, 256, 0, stream>>>(W2, nullptr, W2t, 64, 64);

  // conv composite operator build (3 tiny dense stages)
  k_s9<<<1, 576, 0, stream>>>(Wc2, Wc3, S9);
  k_t729<<<1, 256, 0, stream>>>(S9, Wc1, T729);
  k_m5<<<62, 256, 0, stream>>>(T729, M5T);
  k_beta<<<5, 256, 0, stream>>>(Wc2, Wc3, bc1, bc2, bc3, beta5);

  // sage1: x[ N x128 ] -> yz (y|z), agg -> hA
  k_gemm<128, 128><<<gG, 256, 0, stream>>>(x, Wt1, nullptr, yz, N);
  k_agg<64><<<gA, 256, 0, stream>>>(yz, csr, rowptr, invdeg, bl1, hA, N);
  // sage2: hA -> hB
  k_gemm<128, 64><<<gG, 256, 0, stream>>>(hA, Wt2, nullptr, yz, N);
  k_agg<64><<<gA, 256, 0, stream>>>(yz, csr, rowptr, invdeg, bl2, hB, N);
  // sage3: hB -> hA
  k_gemm<128, 64><<<gG, 256, 0, stream>>>(hB, Wt2, nullptr, yz, N);
  k_agg<64><<<gA, 256, 0, stream>>>(yz, csr, rowptr, invdeg, bl2, hA, N);

  // conv stack + residual (composite banded operator), into yz (reused)
  k_apply<<<gP, 256, 0, stream>>>(hA, M5T, beta5, yz, N);
  // linear2: yz -> hB
  k_gemm<64, 64><<<gG, 256, 0, stream>>>(yz, W2t, b2, hB, N);

  // sage4: hB -> hA
  k_gemm<128, 64><<<gG, 256, 0, stream>>>(hB, Wt2, nullptr, yz, N);
  k_agg<64><<<gA, 256, 0, stream>>>(yz, csr, rowptr, invdeg, bl2, hA, N);
  // sage5: hA -> hB
  k_gemm<128, 64><<<gG, 256, 0, stream>>>(hA, Wt2, nullptr, yz, N);
  k_agg<64><<<gA, 256, 0, stream>>>(yz, csr, rowptr, invdeg, bl2, hB, N);
  // sage6: hB -> d_out (32-dim)
  k_gemm<64, 64><<<gG, 256, 0, stream>>>(hB, Wt3, nullptr, yz, N);
  k_agg<32><<<gA, 256, 0, stream>>>(yz, csr, rowptr, invdeg, bl3, (float*)d_out, N);
}

// Round 8
// 361.838 us; speedup vs baseline: 2.9849x; 1.1700x over previous
//
#include <hip/hip_runtime.h>

#define NN 20000
#define NE 640000

// ---------------- init: zero cursor + edge dtype probe ----------------------
__global__ __launch_bounds__(256) void k_init(const int* __restrict__ ei32,
                                              int* __restrict__ cnt,
                                              int* __restrict__ flag, int N) {
  int i = blockIdx.x * 256 + threadIdx.x;
  if (i < N) cnt[i] = 0;
  if (blockIdx.x == 0 && threadIdx.x < 64) {
    int lane = threadIdx.x;
    int v = ei32[2 * lane + 1];
    unsigned long long nz = __ballot(v != 0);
    if (lane == 0) *flag = (nz == 0ull) ? 2 : 1;  // words per logical element
  }
}

// ----------------------------- CSR build -----------------------------------
__global__ __launch_bounds__(256) void k_hist(const int* __restrict__ ei,
                                              const int* __restrict__ flag,
                                              int* __restrict__ cnt, int E) {
  int st = *flag;
  int e = blockIdx.x * 256 + threadIdx.x;
  if (e < E) atomicAdd(&cnt[ei[(size_t)(E + e) * st]], 1);
}

__global__ __launch_bounds__(256) void k_scanA(const int* __restrict__ cnt,
                                               int* __restrict__ partial, int N) {
  __shared__ int red[4];
  int i = blockIdx.x * 256 + threadIdx.x;
  int v = (i < N) ? cnt[i] : 0;
#pragma unroll
  for (int m = 1; m < 64; m <<= 1) v += __shfl_xor(v, m, 64);
  int wid = threadIdx.x >> 6, lane = threadIdx.x & 63;
  if (lane == 0) red[wid] = v;
  __syncthreads();
  if (threadIdx.x == 0)
    partial[blockIdx.x] = red[0] + red[1] + red[2] + red[3];
}

__global__ __launch_bounds__(128) void k_scanB(const int* __restrict__ partial,
                                               int* __restrict__ prefix,
                                               int* __restrict__ rowptr,
                                               int NB, int E, int N) {
  __shared__ int lds[128];
  int tid = threadIdx.x;
  int mine = (tid < NB) ? partial[tid] : 0;
  lds[tid] = mine;
  __syncthreads();
  for (int off = 1; off < 128; off <<= 1) {
    int v = (tid >= off) ? lds[tid - off] : 0;
    __syncthreads();
    lds[tid] += v;
    __syncthreads();
  }
  if (tid < NB) prefix[tid] = lds[tid] - mine;  // exclusive
  if (tid == 0) rowptr[N] = E;
}

__global__ __launch_bounds__(256) void k_scanC(const int* __restrict__ cnt,
                                               const int* __restrict__ prefix,
                                               int* __restrict__ rowptr,
                                               int* __restrict__ cursor,
                                               float* __restrict__ invdeg, int N) {
  __shared__ int wsum[4];
  int tid = threadIdx.x;
  int i = blockIdx.x * 256 + tid;
  int lane = tid & 63, wid = tid >> 6;
  int dg = (i < N) ? cnt[i] : 0;
  int s = dg;
#pragma unroll
  for (int off = 1; off < 64; off <<= 1) {
    int v = __shfl_up(s, off, 64);
    if (lane >= off) s += v;
  }
  if (lane == 63) wsum[wid] = s;
  __syncthreads();
  int woff = 0;
  for (int w = 0; w < wid; ++w) woff += wsum[w];
  int val = prefix[blockIdx.x] + woff + s - dg;
  if (i < N) {
    rowptr[i] = val;
    cursor[i] = val;
    invdeg[i] = 1.0f / (float)(dg < 1 ? 1 : dg);
  }
}

__global__ __launch_bounds__(256) void k_scatter(const int* __restrict__ ei,
                                                 const int* __restrict__ flag,
                                                 int* __restrict__ cur,
                                                 int* __restrict__ csr, int E) {
  int st = *flag;
  int e = blockIdx.x * 256 + threadIdx.x;
  if (e < E) {
    int d = ei[(size_t)(E + e) * st];
    int p = atomicAdd(&cur[d], 1);
    csr[p] = ei[(size_t)e * st];
  }
}

// ------------------ all weight transposes in one kernel ---------------------
__global__ __launch_bounds__(256) void k_wtransA(
    const float* __restrict__ Wl1, const float* __restrict__ Wr1,
    const float* __restrict__ Wl2, const float* __restrict__ Wr2,
    const float* __restrict__ Wl3, const float* __restrict__ Wr3,
    const float* __restrict__ W2,
    float* __restrict__ Wt1, float* __restrict__ Wt2,
    float* __restrict__ Wt3, float* __restrict__ W2t) {
  int idx = blockIdx.x * 256 + threadIdx.x;
  if (idx < 16384) {                       // Wt1: K=128, C=128
    int w = idx >> 7, u = idx & 127;
    Wt1[idx] = (u < 64) ? Wl1[u * 128 + w] : Wr1[(u - 64) * 128 + w];
  } else if (idx < 24576) {                // Wt2: K=64, C=128
    int t = idx - 16384;
    int w = t >> 7, u = t & 127;
    Wt2[t] = (u < 64) ? Wl2[u * 64 + w] : Wr2[(u - 64) * 64 + w];
  } else if (idx < 28672) {                // Wt3: K=64, C=64
    int t = idx - 24576;
    int w = t >> 6, u = t & 63;
    Wt3[t] = (u < 32) ? Wl3[u * 64 + w] : Wr3[(u - 32) * 64 + w];
  } else {                                 // W2t: K=64, C=64
    int t = idx - 28672;
    int w = t >> 6, u = t & 63;
    W2t[t] = W2[u * 64 + w];
  }
}

__device__ __forceinline__ bool maskB(int var, int o2, int o1) {
  int s = o2 + o1;
  switch (var) {
    case 0: return (o2 >= 0) && (s >= 0);
    case 1: return s >= -1;
    case 3: return s <= 1;
    case 4: return (o2 <= 0) && (s <= 0);
    default: return true;
  }
}

// ----- setup2: b0 = S9+T729; b1-5 = beta variants; b6-38 = Wf + bf ---------
__global__ __launch_bounds__(256) void k_setup2(
    const float* __restrict__ Wc1, const float* __restrict__ Wc2,
    const float* __restrict__ Wc3, const float* __restrict__ bc1,
    const float* __restrict__ bc2, const float* __restrict__ bc3,
    const float* __restrict__ W2t, const float* __restrict__ Wt2,
    const float* __restrict__ b2,
    float* __restrict__ T729, float* __restrict__ beta5,
    float* __restrict__ Wf, float* __restrict__ bf) {
  int b = blockIdx.x, tid = threadIdx.x;
  if (b == 0) {
    __shared__ float W3[576];
    __shared__ float S9s[5184];
    __shared__ float W1s[576];
    for (int e = tid; e < 576; e += 256) { W3[e] = Wc3[e]; W1s[e] = Wc1[e]; }
    __syncthreads();
    for (int bb = tid; bb < 576; bb += 256) {
      float acc[9];
#pragma unroll
      for (int a = 0; a < 9; ++a) acc[a] = 0.0f;
#pragma unroll 4
      for (int o = 0; o < 64; ++o) {
        float w2 = Wc2[o * 576 + bb];
#pragma unroll
        for (int a = 0; a < 9; ++a) acc[a] += W3[o * 9 + a] * w2;
      }
#pragma unroll
      for (int a = 0; a < 9; ++a) S9s[a * 576 + bb] = acc[a];
    }
    __syncthreads();
    for (int c = tid; c < 729; c += 256) {
      int kx0  = c % 3;
      int dl1e = (c / 3) % 3;
      int dl2e = (c / 9) % 3;
      int ky0  = (c / 27) % 3;
      int ky1  = (c / 81) % 3;
      int ky2  = c / 243;
      const float* s9 = &S9s[(ky2 * 3 + dl2e) * 576 + ky1 * 3 + dl1e];
      const float* w1 = &W1s[ky0 * 3 + kx0];
      float t = 0.0f;
#pragma unroll 8
      for (int i = 0; i < 64; ++i) t += s9[i * 9] * w1[i * 9];
      T729[c] = t;
    }
  } else if (b <= 5) {
    __shared__ float S2[576];
    __shared__ float W3b[576];
    __shared__ float B2[64];
    __shared__ float part[256];
    int var = b - 1;
    for (int e = tid; e < 576; e += 256) {
      int o = e / 9, r = e - o * 9;
      float t = 0.0f;
      for (int i = 0; i < 64; ++i) t += Wc2[o * 576 + i * 9 + r] * bc1[i];
      S2[e] = t;
      W3b[e] = Wc3[e];
    }
    if (tid < 64) B2[tid] = bc2[tid];
    __syncthreads();
    int u = tid & 63, oc = tid >> 6;
    float s = 0.0f;
    for (int ky2 = 0; ky2 < 3; ++ky2) {
      int o2 = ky2 - 1;
      bool okA = (var == 0) ? (o2 >= 0) : (var == 4) ? (o2 <= 0) : true;
      if (!okA) continue;
      for (int dl2 = -1; dl2 <= 1; ++dl2) {
        int p = u + dl2; if ((unsigned)p >= 64u) continue;
        float sel[9];
#pragma unroll
        for (int ky1 = 0; ky1 < 3; ++ky1) {
          int o1 = ky1 - 1;
          bool mb = maskB(var, o2, o1);
#pragma unroll
          for (int dl1 = -1; dl1 <= 1; ++dl1) {
            int pq = p + dl1;
            sel[ky1 * 3 + dl1 + 1] = (mb && (unsigned)pq < 64u) ? 1.0f : 0.0f;
          }
        }
#pragma unroll 4
        for (int oo = 0; oo < 16; ++oo) {
          int o = oc * 16 + oo;
          float inner = B2[o];
#pragma unroll
          for (int r = 0; r < 9; ++r) inner += S2[o * 9 + r] * sel[r];
          s += W3b[o * 9 + ky2 * 3 + (dl2 + 1)] * inner;
        }
      }
    }
    part[tid] = s;
    __syncthreads();
    if (tid < 64) {
      beta5[var * 64 + tid] =
          bc3[0] + part[tid] + part[64 + tid] + part[128 + tid] + part[192 + tid];
    }
  } else {
    // Wf[w][u] = sum_k W2t[w*64+k] * Wt2[k*128+u];  bf[u] = sum_k b2[k]*Wt2[k*128+u]
    int gidx = (b - 6) * 256 + tid;
    if (gidx < 8192) {
      int w = gidx >> 7, u = gidx & 127;
      float s = 0.0f;
#pragma unroll 4
      for (int k = 0; k < 64; ++k) s += W2t[w * 64 + k] * Wt2[k * 128 + u];
      Wf[gidx] = s;
    } else if (gidx < 8320) {
      int u = gidx - 8192;
      float s = 0.0f;
#pragma unroll 4
      for (int k = 0; k < 64; ++k) s += b2[k] * Wt2[k * 128 + u];
      bf[u] = s;
    }
  }
}

// Stage 3: M5T[var][d][jw][u] from T729 (LDS table).
__global__ __launch_bounds__(256) void k_m5(const float* __restrict__ T729,
                                            float* __restrict__ M5T) {
  __shared__ float Ts[729];
  int tid = threadIdx.x;
  for (int e = tid; e < 729; e += 256) Ts[e] = T729[e];
  __syncthreads();
  int idx = blockIdx.x * 256 + tid;
  if (idx >= 15680) return;
  int jw = idx % 7;
  int u  = (idx / 7) % 64;
  int d  = (idx / 448) % 7;
  int var = idx / 3136;
  int w = u + jw - 3;
  float s = 0.0f;
  if (w >= 0 && w < 64) {
    for (int ky2 = 0; ky2 < 3; ++ky2) {
      int o2 = ky2 - 1;
      for (int ky1 = 0; ky1 < 3; ++ky1) {
        int o1 = ky1 - 1;
        if (!maskB(var, o2, o1)) continue;
        int o0 = (d - 3) - o2 - o1;
        if (o0 < -1 || o0 > 1) continue;
        int ky0 = o0 + 1;
        int cbase = ((ky2 * 3 + ky1) * 3 + ky0) * 27;
#pragma unroll
        for (int kx0 = 0; kx0 < 3; ++kx0) {
          int jq = jw - kx0;
          if ((unsigned)jq >= 5u) continue;
          int q = u + jq - 2;
          if ((unsigned)q >= 64u) continue;
#pragma unroll
          for (int dl2e = 0; dl2e < 3; ++dl2e) {
            int p = u + dl2e - 1;
            if ((unsigned)p >= 64u) continue;
            int dl1e = jq - dl2e;
            if ((unsigned)dl1e >= 3u) continue;
            s += Ts[cbase + dl2e * 9 + dl1e * 3 + kx0];
          }
        }
      }
    }
  }
  if (d == 3 && jw == 3) s += 1.0f;  // residual: out = conv(h) + h (ONLY here)
  M5T[(var * 49 + d * 7 + jw) * 64 + u] = s;
}

// ----------------------------- dense GEMM -----------------------------------
template <int C, int K>
__global__ __launch_bounds__(256) void k_gemm(const float* __restrict__ X,
                                              const float* __restrict__ Wt,
                                              const float* __restrict__ bias,
                                              float* __restrict__ out, int N) {
  constexpr int ROWS = 16;
  constexpr int RPT = ROWS * C / 256;
  __shared__ float Xs[ROWS * K];
  int y0 = blockIdx.x * ROWS;
  {
    const float4* src = (const float4*)(X + (size_t)y0 * K);
    float4* dst = (float4*)Xs;
#pragma unroll
    for (int v = 0; v < ROWS * K / 4 / 256; ++v)
      dst[v * 256 + threadIdx.x] = src[v * 256 + threadIdx.x];
  }
  __syncthreads();
  int u = threadIdx.x % C;
  int rg = threadIdx.x / C;
  float acc[RPT];
  float bv = bias ? bias[u] : 0.0f;
#pragma unroll
  for (int k = 0; k < RPT; ++k) acc[k] = bv;
#pragma unroll 2
  for (int w0 = 0; w0 < K; w0 += 4) {
    float m0 = Wt[(w0 + 0) * C + u];
    float m1 = Wt[(w0 + 1) * C + u];
    float m2 = Wt[(w0 + 2) * C + u];
    float m3 = Wt[(w0 + 3) * C + u];
    const float* xs = &Xs[(rg * RPT) * K + w0];
#pragma unroll
    for (int k = 0; k < RPT; ++k) {
      float4 h = *(const float4*)(xs + k * K);
      acc[k] += m0 * h.x + m1 * h.y + m2 * h.z + m3 * h.w;
    }
  }
#pragma unroll
  for (int k = 0; k < RPT; ++k)
    out[(size_t)(y0 + rg * RPT + k) * C + u] = acc[k];
}

// ------------------- fused mean-aggregation + GEMM --------------------------
// Block = 16 nodes. Phase 1: wave w aggregates nodes w*4..w*4+3 into LDS
// htile[16][64] (h = mean_agg(y) + bl + z_root). Phase 2: GEMM htile @ Wt.
template <int C>
__global__ __launch_bounds__(256) void k_fused(const float* __restrict__ yzin,
                                               const int* __restrict__ csr,
                                               const int* __restrict__ rowptr,
                                               const float* __restrict__ invdeg,
                                               const float* __restrict__ bl,
                                               const float* __restrict__ Wt,
                                               float* __restrict__ out, int N) {
  constexpr int FV = 16;   // lanes per edge row (64 floats / 4)
  constexpr int G  = 4;    // edge rows per wave chunk
  constexpr int S4 = 32;   // yzin row stride in float4 (128 floats)
  constexpr int CAP = 64;
  __shared__ int idxs[16 * CAP];
  __shared__ float htile[16 * 64];
  int tid = threadIdx.x;
  int w = tid >> 6, lane = tid & 63;
  int base = blockIdx.x * 16;
  int beg_r[4], m_r[4], end_r[4];
#pragma unroll
  for (int rr = 0; rr < 4; ++rr) {
    int node = base + w * 4 + rr;
    int beg = rowptr[node], end = rowptr[node + 1];
    beg_r[rr] = beg; end_r[rr] = end;
    int cnt = end - beg;
    int m = cnt < CAP ? cnt : CAP;
    m_r[rr] = m;
    int* my = &idxs[(w * 4 + rr) * CAP];
    for (int k = lane; k < m; k += 64) my[k] = csr[beg + k];
  }
  __syncthreads();
  int g = lane / FV, f = lane % FV;
  const float4* yz4 = (const float4*)yzin;
#pragma unroll
  for (int rr = 0; rr < 4; ++rr) {
    int node = base + w * 4 + rr;
    const int* my = &idxs[(w * 4 + rr) * CAP];
    int m = m_r[rr];
    float a0x=0,a0y=0,a0z=0,a0w=0, a1x=0,a1y=0,a1z=0,a1w=0;
    float a2x=0,a2y=0,a2z=0,a2w=0, a3x=0,a3y=0,a3z=0,a3w=0;
    int j = g;
    for (; j + 3 * G < m; j += 4 * G) {
      int s0 = my[j], s1 = my[j + G], s2 = my[j + 2 * G], s3 = my[j + 3 * G];
      float4 v0 = yz4[(size_t)s0 * S4 + f];
      float4 v1 = yz4[(size_t)s1 * S4 + f];
      float4 v2 = yz4[(size_t)s2 * S4 + f];
      float4 v3 = yz4[(size_t)s3 * S4 + f];
      a0x += v0.x; a0y += v0.y; a0z += v0.z; a0w += v0.w;
      a1x += v1.x; a1y += v1.y; a1z += v1.z; a1w += v1.w;
      a2x += v2.x; a2y += v2.y; a2z += v2.z; a2w += v2.w;
      a3x += v3.x; a3y += v3.y; a3z += v3.z; a3w += v3.w;
    }
    for (; j < m; j += G) {
      int s0 = my[j];
      float4 v0 = yz4[(size_t)s0 * S4 + f];
      a0x += v0.x; a0y += v0.y; a0z += v0.z; a0w += v0.w;
    }
    for (int jj = beg_r[rr] + CAP + g; jj < end_r[rr]; jj += G) {
      int s0 = csr[jj];
      float4 v0 = yz4[(size_t)s0 * S4 + f];
      a0x += v0.x; a0y += v0.y; a0z += v0.z; a0w += v0.w;
    }
    float ax = (a0x + a1x) + (a2x + a3x);
    float ay = (a0y + a1y) + (a2y + a3y);
    float az = (a0z + a1z) + (a2z + a3z);
    float aw = (a0w + a1w) + (a2w + a3w);
#pragma unroll
    for (int mm = FV; mm < 64; mm <<= 1) {
      ax += __shfl_xor(ax, mm, 64);
      ay += __shfl_xor(ay, mm, 64);
      az += __shfl_xor(az, mm, 64);
      aw += __shfl_xor(aw, mm, 64);
    }
    if (g == 0) {
      float4 root = yz4[(size_t)node * S4 + FV + f];
      float4 bv = ((const float4*)bl)[f];
      float id = invdeg[node];
      float4 o;
      o.x = ax * id + bv.x + root.x;
      o.y = ay * id + bv.y + root.y;
      o.z = az * id + bv.z + root.z;
      o.w = aw * id + bv.w + root.w;
      ((float4*)htile)[(w * 4 + rr) * 16 + f] = o;
    }
  }
  __syncthreads();
  constexpr int RPT = 16 * C / 256;
  int u = tid % C, rg = tid / C;
  float acc[RPT];
#pragma unroll
  for (int k = 0; k < RPT; ++k) acc[k] = 0.0f;
#pragma unroll 2
  for (int w0 = 0; w0 < 64; w0 += 4) {
    float m0 = Wt[(w0 + 0) * C + u];
    float m1 = Wt[(w0 + 1) * C + u];
    float m2 = Wt[(w0 + 2) * C + u];
    float m3 = Wt[(w0 + 3) * C + u];
    const float* xs = &htile[(rg * RPT) * 64 + w0];
#pragma unroll
    for (int k = 0; k < RPT; ++k) {
      float4 h4 = *(const float4*)(xs + k * 64);
      acc[k] += m0 * h4.x + m1 * h4.y + m2 * h4.z + m3 * h4.w;
    }
  }
#pragma unroll
  for (int k = 0; k < RPT; ++k)
    out[(size_t)(base + rg * RPT + k) * C + u] = acc[k];
}

// ---------- fused conv-composite apply + (linear2 ∘ sage4-transform) --------
__global__ __launch_bounds__(256) void k_applyfused(
    const float* __restrict__ h, const float* __restrict__ M5T,
    const float* __restrict__ beta5, const float* __restrict__ Wf,
    const float* __restrict__ bf, float* __restrict__ out, int N) {
  __shared__ float hs[22 * 70];
  __shared__ float htile[16 * 64];
  int tid = threadIdx.x;
  int bstart = blockIdx.x * 16;
  for (int idx = tid; idx < 22 * 70; idx += 256) {
    int row = idx / 70, col = idx - row * 70;
    int y = bstart - 3 + row;
    int ww = col - 3;
    float v = 0.0f;
    if ((unsigned)y < (unsigned)N && (unsigned)ww < 64u)
      v = h[(size_t)y * 64 + ww];
    hs[idx] = v;
  }
  __syncthreads();
  int u = tid & 63, g = tid >> 6;
  int lr0 = g * 4;
  int gstart = bstart + lr0;
  const float* basep = &hs[lr0 * 70 + u];
  bool interior = (gstart >= 2) && (gstart + 3 <= N - 3);
  if (interior) {
    float c[49];
#pragma unroll
    for (int t = 0; t < 49; ++t) c[t] = M5T[(2 * 49 + t) * 64 + u];
    float bet = beta5[2 * 64 + u];
    float acc[4];
#pragma unroll
    for (int k = 0; k < 4; ++k) acc[k] = bet;
#pragma unroll
    for (int rr = 0; rr < 10; ++rr) {
      float t7[7];
#pragma unroll
      for (int jw = 0; jw < 7; ++jw) t7[jw] = basep[rr * 70 + jw];
#pragma unroll
      for (int d = 0; d < 7; ++d) {
        int k = rr - d;  // compile-time per unrolled (rr,d)
        if (k >= 0 && k < 4) {
#pragma unroll
          for (int jw = 0; jw < 7; ++jw) acc[k] += c[d * 7 + jw] * t7[jw];
        }
      }
    }
#pragma unroll
    for (int k = 0; k < 4; ++k) htile[(lr0 + k) * 64 + u] = acc[k];
  } else {
    for (int k = 0; k < 4; ++k) {
      int y = gstart + k;
      int var = (y == 0) ? 0 : (y == 1) ? 1 : (y == N - 2) ? 3 : (y == N - 1) ? 4 : 2;
      float acc = beta5[var * 64 + u];
      for (int d = 0; d < 7; ++d)
        for (int jw = 0; jw < 7; ++jw)
          acc += M5T[(var * 49 + d * 7 + jw) * 64 + u] * basep[(k + d) * 70 + jw];
      htile[(lr0 + k) * 64 + u] = acc;
    }
  }
  __syncthreads();
  // gemm: htile[16x64] @ Wf[64x128] + bf
  int u2 = tid % 128, rg = tid / 128;
  float acc2[8];
  float bv = bf[u2];
#pragma unroll
  for (int k = 0; k < 8; ++k) acc2[k] = bv;
#pragma unroll 2
  for (int w0 = 0; w0 < 64; w0 += 4) {
    float m0 = Wf[(w0 + 0) * 128 + u2];
    float m1 = Wf[(w0 + 1) * 128 + u2];
    float m2 = Wf[(w0 + 2) * 128 + u2];
    float m3 = Wf[(w0 + 3) * 128 + u2];
    const float* xs = &htile[(rg * 8) * 64 + w0];
#pragma unroll
    for (int k = 0; k < 8; ++k) {
      float4 h4 = *(const float4*)(xs + k * 64);
      acc2[k] += m0 * h4.x + m1 * h4.y + m2 * h4.z + m3 * h4.w;
    }
  }
#pragma unroll
  for (int k = 0; k < 8; ++k)
    out[(size_t)(bstart + rg * 8 + k) * 128 + u2] = acc2[k];
}

// ------------------ standalone mean aggregation (agg3, agg6) ----------------
template <int DH>
__global__ __launch_bounds__(256) void k_agg(const float* __restrict__ yz,
                                             const int* __restrict__ csr,
                                             const int* __restrict__ rowptr,
                                             const float* __restrict__ invdeg,
                                             const float* __restrict__ bl,
                                             float* __restrict__ out, int N) {
  constexpr int FV = DH / 4;
  constexpr int G  = 64 / FV;
  constexpr int S4 = DH / 2;
  constexpr int CAP = 256;
  __shared__ int idxs[4 * CAP];
  int wid = threadIdx.x >> 6, lane = threadIdx.x & 63;
  int node = blockIdx.x * 4 + wid;
  int beg = rowptr[node], end = rowptr[node + 1];
  int cnt = end - beg;
  int m = cnt < CAP ? cnt : CAP;
  int* my = &idxs[wid * CAP];
  for (int k = lane; k < m; k += 64) my[k] = csr[beg + k];
  __syncthreads();
  int g = lane / FV, f = lane % FV;
  const float4* yz4 = (const float4*)yz;
  float a0x=0,a0y=0,a0z=0,a0w=0, a1x=0,a1y=0,a1z=0,a1w=0;
  float a2x=0,a2y=0,a2z=0,a2w=0, a3x=0,a3y=0,a3z=0,a3w=0;
  int j = g;
  for (; j + 3 * G < m; j += 4 * G) {
    int s0 = my[j], s1 = my[j + G], s2 = my[j + 2 * G], s3 = my[j + 3 * G];
    float4 v0 = yz4[(size_t)s0 * S4 + f];
    float4 v1 = yz4[(size_t)s1 * S4 + f];
    float4 v2 = yz4[(size_t)s2 * S4 + f];
    float4 v3 = yz4[(size_t)s3 * S4 + f];
    a0x += v0.x; a0y += v0.y; a0z += v0.z; a0w += v0.w;
    a1x += v1.x; a1y += v1.y; a1z += v1.z; a1w += v1.w;
    a2x += v2.x; a2y += v2.y; a2z += v2.z; a2w += v2.w;
    a3x += v3.x; a3y += v3.y; a3z += v3.z; a3w += v3.w;
  }
  for (; j < m; j += G) {
    int s0 = my[j];
    float4 v0 = yz4[(size_t)s0 * S4 + f];
    a0x += v0.x; a0y += v0.y; a0z += v0.z; a0w += v0.w;
  }
  for (int jj = beg + CAP + g; jj < end; jj += G) {
    int s0 = csr[jj];
    float4 v0 = yz4[(size_t)s0 * S4 + f];
    a0x += v0.x; a0y += v0.y; a0z += v0.z; a0w += v0.w;
  }
  float ax = (a0x + a1x) + (a2x + a3x);
  float ay = (a0y + a1y) + (a2y + a3y);
  float az = (a0z + a1z) + (a2z + a3z);
  float aw = (a0w + a1w) + (a2w + a3w);
#pragma unroll
  for (int mm = FV; mm < 64; mm <<= 1) {
    ax += __shfl_xor(ax, mm, 64);
    ay += __shfl_xor(ay, mm, 64);
    az += __shfl_xor(az, mm, 64);
    aw += __shfl_xor(aw, mm, 64);
  }
  if (g == 0) {
    float4 root = yz4[(size_t)node * S4 + FV + f];
    float4 bv = ((const float4*)bl)[f];
    float id = invdeg[node];
    float4 o;
    o.x = ax * id + bv.x + root.x;
    o.y = ay * id + bv.y + root.y;
    o.z = az * id + bv.z + root.z;
    o.w = aw * id + bv.w + root.w;
    ((float4*)out)[(size_t)node * FV + f] = o;
  }
}

// ------------------------------- launcher -----------------------------------
extern "C" void kernel_launch(void* const* d_in, const int* in_sizes, int n_in,
                              void* d_out, int out_size, void* d_ws, size_t ws_size,
                              hipStream_t stream) {
  const int N = NN, E = NE;
  const float* x   = (const float*)d_in[0];
  const int*   ei  = (const int*)d_in[1];
  const float* Wl1 = (const float*)d_in[2];
  const float* bl1 = (const float*)d_in[3];
  const float* Wr1 = (const float*)d_in[4];
  const float* Wl2 = (const float*)d_in[5];
  const float* bl2 = (const float*)d_in[6];
  const float* Wr2 = (const float*)d_in[7];
  const float* Wl3 = (const float*)d_in[8];
  const float* bl3 = (const float*)d_in[9];
  const float* Wr3 = (const float*)d_in[10];
  const float* Wc1 = (const float*)d_in[11];
  const float* bc1 = (const float*)d_in[12];
  const float* Wc2 = (const float*)d_in[13];
  const float* bc2 = (const float*)d_in[14];
  const float* Wc3 = (const float*)d_in[15];
  const float* bc3 = (const float*)d_in[16];
  const float* W2  = (const float*)d_in[17];
  const float* b2  = (const float*)d_in[18];

  char* ws = (char*)d_ws;
  size_t off = 0;
  auto alloc = [&](size_t bytes) -> void* {
    off = (off + 255) & ~(size_t)255;
    void* p = ws + off;
    off += bytes;
    return p;
  };
  int*   eflag  = (int*)alloc(4);
  int*   rowptr = (int*)alloc((size_t)(N + 1) * 4);
  int*   cursor = (int*)alloc((size_t)N * 4);
  float* invdeg = (float*)alloc((size_t)N * 4);
  int*   csr    = (int*)alloc((size_t)E * 4);
  int*   partial= (int*)alloc(128 * 4);
  int*   prefix = (int*)alloc(128 * 4);
  float* Wt1    = (float*)alloc(128 * 128 * 4);
  float* Wt2    = (float*)alloc(64 * 128 * 4);
  float* Wt3    = (float*)alloc(64 * 64 * 4);
  float* W2t    = (float*)alloc(64 * 64 * 4);
  float* Wf     = (float*)alloc(64 * 128 * 4);
  float* bf     = (float*)alloc(128 * 4);
  float* T729   = (float*)alloc(729 * 4);
  float* M5T    = (float*)alloc(15680 * 4);
  float* beta5  = (float*)alloc(320 * 4);
  float* yzA    = (float*)alloc((size_t)N * 128 * 4);
  float* yzB    = (float*)alloc((size_t)N * 128 * 4);
  float* hA     = (float*)alloc((size_t)N * 64 * 4);
  (void)ws_size; (void)in_sizes; (void)n_in; (void)out_size;

  const int gE = (E + 255) / 256;  // 2500
  const int gF = N / 16;           // 1250
  const int gA = N / 4;            // 5000
  const int gS = (N + 255) / 256;  // 79

  // CSR build (once; shared by all 6 sage layers)
  k_init<<<gS, 256, 0, stream>>>(ei, cursor, eflag, N);
  k_hist<<<gE, 256, 0, stream>>>(ei, eflag, cursor, E);
  k_scanA<<<gS, 256, 0, stream>>>(cursor, partial, N);
  k_scanB<<<1, 128, 0, stream>>>(partial, prefix, rowptr, gS, E, N);
  k_scanC<<<gS, 256, 0, stream>>>(cursor, prefix, rowptr, cursor, invdeg, N);
  k_scatter<<<gE, 256, 0, stream>>>(ei, eflag, cursor, csr, E);

  // weight prep + conv composite build
  k_wtransA<<<128, 256, 0, stream>>>(Wl1, Wr1, Wl2, Wr2, Wl3, Wr3, W2,
                                     Wt1, Wt2, Wt3, W2t);
  k_setup2<<<39, 256, 0, stream>>>(Wc1, Wc2, Wc3, bc1, bc2, bc3, W2t, Wt2, b2,
                                   T729, beta5, Wf, bf);
  k_m5<<<62, 256, 0, stream>>>(T729, M5T);

  // sage1 transform
  k_gemm<128, 128><<<gF, 256, 0, stream>>>(x, Wt1, nullptr, yzA, N);
  // [agg1 + sage2-transform]
  k_fused<128><<<gF, 256, 0, stream>>>(yzA, csr, rowptr, invdeg, bl1, Wt2, yzB, N);
  // [agg2 + sage3-transform]
  k_fused<128><<<gF, 256, 0, stream>>>(yzB, csr, rowptr, invdeg, bl2, Wt2, yzA, N);
  // agg3 -> hA
  k_agg<64><<<gA, 256, 0, stream>>>(yzA, csr, rowptr, invdeg, bl2, hA, N);
  // [conv-composite + residual + linear2 + sage4-transform]
  k_applyfused<<<gF, 256, 0, stream>>>(hA, M5T, beta5, Wf, bf, yzB, N);
  // [agg4 + sage5-transform]
  k_fused<128><<<gF, 256, 0, stream>>>(yzB, csr, rowptr, invdeg, bl2, Wt2, yzA, N);
  // [agg5 + sage6-transform]
  k_fused<64><<<gF, 256, 0, stream>>>(yzA, csr, rowptr, invdeg, bl2, Wt3, yzB, N);
  // agg6 -> d_out (32-dim)
  k_agg<32><<<gA, 256, 0, stream>>>(yzB, csr, rowptr, invdeg, bl3, (float*)d_out, N);
}

// Round 9
// 357.516 us; speedup vs baseline: 3.0210x; 1.0121x over previous
//
#include <hip/hip_runtime.h>

#define NN 20000
#define NE 640000
#define NBUK 79  // ceil(20000/256) buckets of 256 nodes

// ---------------- init: zero cursor + edge dtype probe ----------------------
__global__ __launch_bounds__(256) void k_init(const int* __restrict__ ei32,
                                              int* __restrict__ cnt,
                                              int* __restrict__ flag, int N) {
  int i = blockIdx.x * 256 + threadIdx.x;
  if (i < N) cnt[i] = 0;
  if (blockIdx.x == 0 && threadIdx.x < 64) {
    int lane = threadIdx.x;
    int v = ei32[2 * lane + 1];
    unsigned long long nz = __ballot(v != 0);
    if (lane == 0) *flag = (nz == 0ull) ? 2 : 1;  // words per logical element
  }
}

// ----------------------------- CSR build -----------------------------------
__global__ __launch_bounds__(256) void k_hist(const int* __restrict__ ei,
                                              const int* __restrict__ flag,
                                              int* __restrict__ cnt, int E) {
  int st = *flag;
  int e = blockIdx.x * 256 + threadIdx.x;
  if (e < E) atomicAdd(&cnt[ei[(size_t)(E + e) * st]], 1);
}

__global__ __launch_bounds__(256) void k_scanA(const int* __restrict__ cnt,
                                               int* __restrict__ partial, int N) {
  __shared__ int red[4];
  int i = blockIdx.x * 256 + threadIdx.x;
  int v = (i < N) ? cnt[i] : 0;
#pragma unroll
  for (int m = 1; m < 64; m <<= 1) v += __shfl_xor(v, m, 64);
  int wid = threadIdx.x >> 6, lane = threadIdx.x & 63;
  if (lane == 0) red[wid] = v;
  __syncthreads();
  if (threadIdx.x == 0)
    partial[blockIdx.x] = red[0] + red[1] + red[2] + red[3];
}

__global__ __launch_bounds__(128) void k_scanB(const int* __restrict__ partial,
                                               int* __restrict__ prefix,
                                               int* __restrict__ rowptr,
                                               int NB, int E, int N) {
  __shared__ int lds[128];
  int tid = threadIdx.x;
  int mine = (tid < NB) ? partial[tid] : 0;
  lds[tid] = mine;
  __syncthreads();
  for (int off = 1; off < 128; off <<= 1) {
    int v = (tid >= off) ? lds[tid - off] : 0;
    __syncthreads();
    lds[tid] += v;
    __syncthreads();
  }
  if (tid < NB) prefix[tid] = lds[tid] - mine;  // exclusive
  if (tid == 0) rowptr[N] = E;
}

// Phase C: also initializes the 79 bucket cursors (bcur[b] = rowptr[b*256]).
__global__ __launch_bounds__(256) void k_scanC(const int* __restrict__ cnt,
                                               const int* __restrict__ prefix,
                                               int* __restrict__ rowptr,
                                               int* __restrict__ cursor,
                                               float* __restrict__ invdeg,
                                               int* __restrict__ bcur, int N) {
  __shared__ int wsum[4];
  int tid = threadIdx.x;
  int i = blockIdx.x * 256 + tid;
  int lane = tid & 63, wid = tid >> 6;
  int dg = (i < N) ? cnt[i] : 0;
  int s = dg;
#pragma unroll
  for (int off = 1; off < 64; off <<= 1) {
    int v = __shfl_up(s, off, 64);
    if (lane >= off) s += v;
  }
  if (lane == 63) wsum[wid] = s;
  __syncthreads();
  int woff = 0;
  for (int w = 0; w < wid; ++w) woff += wsum[w];
  int val = prefix[blockIdx.x] + woff + s - dg;
  if (i < N) {
    rowptr[i] = val;
    cursor[i] = val;
    invdeg[i] = 1.0f / (float)(dg < 1 ? 1 : dg);
    if ((i & 255) == 0) bcur[i >> 8] = val;
  }
}

// Pass 1: bucket-partition edges by dst>>8 into ebuf (coalesced chunk writes).
__global__ __launch_bounds__(256) void k_part(const int* __restrict__ ei,
                                              const int* __restrict__ flag,
                                              int* __restrict__ bcur,
                                              unsigned long long* __restrict__ ebuf,
                                              int E) {
  __shared__ int lcnt[NBUK];
  __shared__ int lbase[NBUK];
  int tid = threadIdx.x;
  for (int i = tid; i < NBUK; i += 256) lcnt[i] = 0;
  __syncthreads();
  int st = *flag;
  int e0 = blockIdx.x * 4096;
  int srcv[16], dstv[16], lrank[16], bk[16];
  int n = 0;
#pragma unroll
  for (int t = 0; t < 16; ++t) {
    int e = e0 + t * 256 + tid;
    if (e < E) {
      int s = ei[(size_t)e * st];
      int d = ei[(size_t)(E + e) * st];
      int b = d >> 8;
      srcv[n] = s; dstv[n] = d; bk[n] = b;
      lrank[n] = atomicAdd(&lcnt[b], 1);
      ++n;
    }
  }
  __syncthreads();
  for (int i = tid; i < NBUK; i += 256)
    lbase[i] = atomicAdd(&bcur[i], lcnt[i]);
  __syncthreads();
  for (int t = 0; t < n; ++t) {
    int pos = lbase[bk[t]] + lrank[t];
    ebuf[pos] = ((unsigned long long)(unsigned)dstv[t] << 32) | (unsigned)srcv[t];
  }
}

// Pass 2: scatter within L2-resident ~32KB bucket windows (no line thrash).
__global__ __launch_bounds__(256) void k_scatter2(
    const unsigned long long* __restrict__ ebuf,
    int* __restrict__ cursor, int* __restrict__ csr, int E) {
  int e = blockIdx.x * 256 + threadIdx.x;
  if (e < E) {
    unsigned long long pk = ebuf[e];
    int s = (int)(unsigned)pk;
    int d = (int)(pk >> 32);
    int p = atomicAdd(&cursor[d], 1);
    csr[p] = s;
  }
}

// ------------------ all weight transposes in one kernel ---------------------
__global__ __launch_bounds__(256) void k_wtransA(
    const float* __restrict__ Wl1, const float* __restrict__ Wr1,
    const float* __restrict__ Wl2, const float* __restrict__ Wr2,
    const float* __restrict__ Wl3, const float* __restrict__ Wr3,
    const float* __restrict__ W2,
    float* __restrict__ Wt1, float* __restrict__ Wt2,
    float* __restrict__ Wt3, float* __restrict__ W2t) {
  int idx = blockIdx.x * 256 + threadIdx.x;
  if (idx < 16384) {                       // Wt1: K=128, C=128
    int w = idx >> 7, u = idx & 127;
    Wt1[idx] = (u < 64) ? Wl1[u * 128 + w] : Wr1[(u - 64) * 128 + w];
  } else if (idx < 24576) {                // Wt2: K=64, C=128
    int t = idx - 16384;
    int w = t >> 7, u = t & 127;
    Wt2[t] = (u < 64) ? Wl2[u * 64 + w] : Wr2[(u - 64) * 64 + w];
  } else if (idx < 28672) {                // Wt3: K=64, C=64
    int t = idx - 24576;
    int w = t >> 6, u = t & 63;
    Wt3[t] = (u < 32) ? Wl3[u * 64 + w] : Wr3[(u - 32) * 64 + w];
  } else {                                 // W2t: K=64, C=64
    int t = idx - 28672;
    int w = t >> 6, u = t & 63;
    W2t[t] = W2[u * 64 + w];
  }
}

__device__ __forceinline__ bool maskB(int var, int o2, int o1) {
  int s = o2 + o1;
  switch (var) {
    case 0: return (o2 >= 0) && (s >= 0);
    case 1: return s >= -1;
    case 3: return s <= 1;
    case 4: return (o2 <= 0) && (s <= 0);
    default: return true;
  }
}

// ----- setup2: b0 = S9+T729; b1-5 = beta variants; b6-38 = Wf + bf ---------
__global__ __launch_bounds__(256) void k_setup2(
    const float* __restrict__ Wc1, const float* __restrict__ Wc2,
    const float* __restrict__ Wc3, const float* __restrict__ bc1,
    const float* __restrict__ bc2, const float* __restrict__ bc3,
    const float* __restrict__ W2t, const float* __restrict__ Wt2,
    const float* __restrict__ b2,
    float* __restrict__ T729, float* __restrict__ beta5,
    float* __restrict__ Wf, float* __restrict__ bf) {
  int b = blockIdx.x, tid = threadIdx.x;
  if (b == 0) {
    __shared__ float W3[576];
    __shared__ float S9s[5184];
    __shared__ float W1s[576];
    for (int e = tid; e < 576; e += 256) { W3[e] = Wc3[e]; W1s[e] = Wc1[e]; }
    __syncthreads();
    for (int bb = tid; bb < 576; bb += 256) {
      float acc[9];
#pragma unroll
      for (int a = 0; a < 9; ++a) acc[a] = 0.0f;
#pragma unroll 4
      for (int o = 0; o < 64; ++o) {
        float w2 = Wc2[o * 576 + bb];
#pragma unroll
        for (int a = 0; a < 9; ++a) acc[a] += W3[o * 9 + a] * w2;
      }
#pragma unroll
      for (int a = 0; a < 9; ++a) S9s[a * 576 + bb] = acc[a];
    }
    __syncthreads();
    for (int c = tid; c < 729; c += 256) {
      int kx0  = c % 3;
      int dl1e = (c / 3) % 3;
      int dl2e = (c / 9) % 3;
      int ky0  = (c / 27) % 3;
      int ky1  = (c / 81) % 3;
      int ky2  = c / 243;
      const float* s9 = &S9s[(ky2 * 3 + dl2e) * 576 + ky1 * 3 + dl1e];
      const float* w1 = &W1s[ky0 * 3 + kx0];
      float t = 0.0f;
#pragma unroll 8
      for (int i = 0; i < 64; ++i) t += s9[i * 9] * w1[i * 9];
      T729[c] = t;
    }
  } else if (b <= 5) {
    __shared__ float S2[576];
    __shared__ float W3b[576];
    __shared__ float B2[64];
    __shared__ float part[256];
    int var = b - 1;
    for (int e = tid; e < 576; e += 256) {
      int o = e / 9, r = e - o * 9;
      float t = 0.0f;
      for (int i = 0; i < 64; ++i) t += Wc2[o * 576 + i * 9 + r] * bc1[i];
      S2[e] = t;
      W3b[e] = Wc3[e];
    }
    if (tid < 64) B2[tid] = bc2[tid];
    __syncthreads();
    int u = tid & 63, oc = tid >> 6;
    float s = 0.0f;
    for (int ky2 = 0; ky2 < 3; ++ky2) {
      int o2 = ky2 - 1;
      bool okA = (var == 0) ? (o2 >= 0) : (var == 4) ? (o2 <= 0) : true;
      if (!okA) continue;
      for (int dl2 = -1; dl2 <= 1; ++dl2) {
        int p = u + dl2; if ((unsigned)p >= 64u) continue;
        float sel[9];
#pragma unroll
        for (int ky1 = 0; ky1 < 3; ++ky1) {
          int o1 = ky1 - 1;
          bool mb = maskB(var, o2, o1);
#pragma unroll
          for (int dl1 = -1; dl1 <= 1; ++dl1) {
            int pq = p + dl1;
            sel[ky1 * 3 + dl1 + 1] = (mb && (unsigned)pq < 64u) ? 1.0f : 0.0f;
          }
        }
#pragma unroll 4
        for (int oo = 0; oo < 16; ++oo) {
          int o = oc * 16 + oo;
          float inner = B2[o];
#pragma unroll
          for (int r = 0; r < 9; ++r) inner += S2[o * 9 + r] * sel[r];
          s += W3b[o * 9 + ky2 * 3 + (dl2 + 1)] * inner;
        }
      }
    }
    part[tid] = s;
    __syncthreads();
    if (tid < 64) {
      beta5[var * 64 + tid] =
          bc3[0] + part[tid] + part[64 + tid] + part[128 + tid] + part[192 + tid];
    }
  } else {
    int gidx = (b - 6) * 256 + tid;
    if (gidx < 8192) {
      int w = gidx >> 7, u = gidx & 127;
      float s = 0.0f;
#pragma unroll 4
      for (int k = 0; k < 64; ++k) s += W2t[w * 64 + k] * Wt2[k * 128 + u];
      Wf[gidx] = s;
    } else if (gidx < 8320) {
      int u = gidx - 8192;
      float s = 0.0f;
#pragma unroll 4
      for (int k = 0; k < 64; ++k) s += b2[k] * Wt2[k * 128 + u];
      bf[u] = s;
    }
  }
}

// Stage 3: M5T[var][d][jw][u] from T729 (LDS table).
__global__ __launch_bounds__(256) void k_m5(const float* __restrict__ T729,
                                            float* __restrict__ M5T) {
  __shared__ float Ts[729];
  int tid = threadIdx.x;
  for (int e = tid; e < 729; e += 256) Ts[e] = T729[e];
  __syncthreads();
  int idx = blockIdx.x * 256 + tid;
  if (idx >= 15680) return;
  int jw = idx % 7;
  int u  = (idx / 7) % 64;
  int d  = (idx / 448) % 7;
  int var = idx / 3136;
  int w = u + jw - 3;
  float s = 0.0f;
  if (w >= 0 && w < 64) {
    for (int ky2 = 0; ky2 < 3; ++ky2) {
      int o2 = ky2 - 1;
      for (int ky1 = 0; ky1 < 3; ++ky1) {
        int o1 = ky1 - 1;
        if (!maskB(var, o2, o1)) continue;
        int o0 = (d - 3) - o2 - o1;
        if (o0 < -1 || o0 > 1) continue;
        int ky0 = o0 + 1;
        int cbase = ((ky2 * 3 + ky1) * 3 + ky0) * 27;
#pragma unroll
        for (int kx0 = 0; kx0 < 3; ++kx0) {
          int jq = jw - kx0;
          if ((unsigned)jq >= 5u) continue;
          int q = u + jq - 2;
          if ((unsigned)q >= 64u) continue;
#pragma unroll
          for (int dl2e = 0; dl2e < 3; ++dl2e) {
            int p = u + dl2e - 1;
            if ((unsigned)p >= 64u) continue;
            int dl1e = jq - dl2e;
            if ((unsigned)dl1e >= 3u) continue;
            s += Ts[cbase + dl2e * 9 + dl1e * 3 + kx0];
          }
        }
      }
    }
  }
  if (d == 3 && jw == 3) s += 1.0f;  // residual: out = conv(h) + h (ONLY here)
  M5T[(var * 49 + d * 7 + jw) * 64 + u] = s;
}

// ----------------------------- dense GEMM -----------------------------------
template <int C, int K>
__global__ __launch_bounds__(256) void k_gemm(const float* __restrict__ X,
                                              const float* __restrict__ Wt,
                                              const float* __restrict__ bias,
                                              float* __restrict__ out, int N) {
  constexpr int ROWS = 16;
  constexpr int RPT = ROWS * C / 256;
  __shared__ float Xs[ROWS * K];
  int y0 = blockIdx.x * ROWS;
  {
    const float4* src = (const float4*)(X + (size_t)y0 * K);
    float4* dst = (float4*)Xs;
#pragma unroll
    for (int v = 0; v < ROWS * K / 4 / 256; ++v)
      dst[v * 256 + threadIdx.x] = src[v * 256 + threadIdx.x];
  }
  __syncthreads();
  int u = threadIdx.x % C;
  int rg = threadIdx.x / C;
  float acc[RPT];
  float bv = bias ? bias[u] : 0.0f;
#pragma unroll
  for (int k = 0; k < RPT; ++k) acc[k] = bv;
#pragma unroll 2
  for (int w0 = 0; w0 < K; w0 += 4) {
    float m0 = Wt[(w0 + 0) * C + u];
    float m1 = Wt[(w0 + 1) * C + u];
    float m2 = Wt[(w0 + 2) * C + u];
    float m3 = Wt[(w0 + 3) * C + u];
    const float* xs = &Xs[(rg * RPT) * K + w0];
#pragma unroll
    for (int k = 0; k < RPT; ++k) {
      float4 h = *(const float4*)(xs + k * K);
      acc[k] += m0 * h.x + m1 * h.y + m2 * h.z + m3 * h.w;
    }
  }
#pragma unroll
  for (int k = 0; k < RPT; ++k)
    out[(size_t)(y0 + rg * RPT + k) * C + u] = acc[k];
}

// ------------------- fused mean-aggregation + GEMM --------------------------
template <int C>
__global__ __launch_bounds__(256) void k_fused(const float* __restrict__ yzin,
                                               const int* __restrict__ csr,
                                               const int* __restrict__ rowptr,
                                               const float* __restrict__ invdeg,
                                               const float* __restrict__ bl,
                                               const float* __restrict__ Wt,
                                               float* __restrict__ out, int N) {
  constexpr int FV = 16;
  constexpr int G  = 4;
  constexpr int S4 = 32;
  constexpr int CAP = 64;
  __shared__ int idxs[16 * CAP];
  __shared__ float htile[16 * 64];
  int tid = threadIdx.x;
  int w = tid >> 6, lane = tid & 63;
  int base = blockIdx.x * 16;
  int beg_r[4], m_r[4], end_r[4];
#pragma unroll
  for (int rr = 0; rr < 4; ++rr) {
    int node = base + w * 4 + rr;
    int beg = rowptr[node], end = rowptr[node + 1];
    beg_r[rr] = beg; end_r[rr] = end;
    int cnt = end - beg;
    int m = cnt < CAP ? cnt : CAP;
    m_r[rr] = m;
    int* my = &idxs[(w * 4 + rr) * CAP];
    for (int k = lane; k < m; k += 64) my[k] = csr[beg + k];
  }
  __syncthreads();
  int g = lane / FV, f = lane % FV;
  const float4* yz4 = (const float4*)yzin;
#pragma unroll
  for (int rr = 0; rr < 4; ++rr) {
    int node = base + w * 4 + rr;
    const int* my = &idxs[(w * 4 + rr) * CAP];
    int m = m_r[rr];
    float a0x=0,a0y=0,a0z=0,a0w=0, a1x=0,a1y=0,a1z=0,a1w=0;
    float a2x=0,a2y=0,a2z=0,a2w=0, a3x=0,a3y=0,a3z=0,a3w=0;
    int j = g;
    for (; j + 3 * G < m; j += 4 * G) {
      int s0 = my[j], s1 = my[j + G], s2 = my[j + 2 * G], s3 = my[j + 3 * G];
      float4 v0 = yz4[(size_t)s0 * S4 + f];
      float4 v1 = yz4[(size_t)s1 * S4 + f];
      float4 v2 = yz4[(size_t)s2 * S4 + f];
      float4 v3 = yz4[(size_t)s3 * S4 + f];
      a0x += v0.x; a0y += v0.y; a0z += v0.z; a0w += v0.w;
      a1x += v1.x; a1y += v1.y; a1z += v1.z; a1w += v1.w;
      a2x += v2.x; a2y += v2.y; a2z += v2.z; a2w += v2.w;
      a3x += v3.x; a3y += v3.y; a3z += v3.z; a3w += v3.w;
    }
    for (; j < m; j += G) {
      int s0 = my[j];
      float4 v0 = yz4[(size_t)s0 * S4 + f];
      a0x += v0.x; a0y += v0.y; a0z += v0.z; a0w += v0.w;
    }
    for (int jj = beg_r[rr] + CAP + g; jj < end_r[rr]; jj += G) {
      int s0 = csr[jj];
      float4 v0 = yz4[(size_t)s0 * S4 + f];
      a0x += v0.x; a0y += v0.y; a0z += v0.z; a0w += v0.w;
    }
    float ax = (a0x + a1x) + (a2x + a3x);
    float ay = (a0y + a1y) + (a2y + a3y);
    float az = (a0z + a1z) + (a2z + a3z);
    float aw = (a0w + a1w) + (a2w + a3w);
#pragma unroll
    for (int mm = FV; mm < 64; mm <<= 1) {
      ax += __shfl_xor(ax, mm, 64);
      ay += __shfl_xor(ay, mm, 64);
      az += __shfl_xor(az, mm, 64);
      aw += __shfl_xor(aw, mm, 64);
    }
    if (g == 0) {
      float4 root = yz4[(size_t)node * S4 + FV + f];
      float4 bv = ((const float4*)bl)[f];
      float id = invdeg[node];
      float4 o;
      o.x = ax * id + bv.x + root.x;
      o.y = ay * id + bv.y + root.y;
      o.z = az * id + bv.z + root.z;
      o.w = aw * id + bv.w + root.w;
      ((float4*)htile)[(w * 4 + rr) * 16 + f] = o;
    }
  }
  __syncthreads();
  constexpr int RPT = 16 * C / 256;
  int u = tid % C, rg = tid / C;
  float acc[RPT];
#pragma unroll
  for (int k = 0; k < RPT; ++k) acc[k] = 0.0f;
#pragma unroll 2
  for (int w0 = 0; w0 < 64; w0 += 4) {
    float m0 = Wt[(w0 + 0) * C + u];
    float m1 = Wt[(w0 + 1) * C + u];
    float m2 = Wt[(w0 + 2) * C + u];
    float m3 = Wt[(w0 + 3) * C + u];
    const float* xs = &htile[(rg * RPT) * 64 + w0];
#pragma unroll
    for (int k = 0; k < RPT; ++k) {
      float4 h4 = *(const float4*)(xs + k * 64);
      acc[k] += m0 * h4.x + m1 * h4.y + m2 * h4.z + m3 * h4.w;
    }
  }
#pragma unroll
  for (int k = 0; k < RPT; ++k)
    out[(size_t)(base + rg * RPT + k) * C + u] = acc[k];
}

// ---------- fused conv-composite apply + (linear2 ∘ sage4-transform) --------
__global__ __launch_bounds__(256) void k_applyfused(
    const float* __restrict__ h, const float* __restrict__ M5T,
    const float* __restrict__ beta5, const float* __restrict__ Wf,
    const float* __restrict__ bf, float* __restrict__ out, int N) {
  __shared__ float hs[22 * 70];
  __shared__ float htile[16 * 64];
  int tid = threadIdx.x;
  int bstart = blockIdx.x * 16;
  for (int idx = tid; idx < 22 * 70; idx += 256) {
    int row = idx / 70, col = idx - row * 70;
    int y = bstart - 3 + row;
    int ww = col - 3;
    float v = 0.0f;
    if ((unsigned)y < (unsigned)N && (unsigned)ww < 64u)
      v = h[(size_t)y * 64 + ww];
    hs[idx] = v;
  }
  __syncthreads();
  int u = tid & 63, g = tid >> 6;
  int lr0 = g * 4;
  int gstart = bstart + lr0;
  const float* basep = &hs[lr0 * 70 + u];
  bool interior = (gstart >= 2) && (gstart + 3 <= N - 3);
  if (interior) {
    float c[49];
#pragma unroll
    for (int t = 0; t < 49; ++t) c[t] = M5T[(2 * 49 + t) * 64 + u];
    float bet = beta5[2 * 64 + u];
    float acc[4];
#pragma unroll
    for (int k = 0; k < 4; ++k) acc[k] = bet;
#pragma unroll
    for (int rr = 0; rr < 10; ++rr) {
      float t7[7];
#pragma unroll
      for (int jw = 0; jw < 7; ++jw) t7[jw] = basep[rr * 70 + jw];
#pragma unroll
      for (int d = 0; d < 7; ++d) {
        int k = rr - d;
        if (k >= 0 && k < 4) {
#pragma unroll
          for (int jw = 0; jw < 7; ++jw) acc[k] += c[d * 7 + jw] * t7[jw];
        }
      }
    }
#pragma unroll
    for (int k = 0; k < 4; ++k) htile[(lr0 + k) * 64 + u] = acc[k];
  } else {
    for (int k = 0; k < 4; ++k) {
      int y = gstart + k;
      int var = (y == 0) ? 0 : (y == 1) ? 1 : (y == N - 2) ? 3 : (y == N - 1) ? 4 : 2;
      float acc = beta5[var * 64 + u];
      for (int d = 0; d < 7; ++d)
        for (int jw = 0; jw < 7; ++jw)
          acc += M5T[(var * 49 + d * 7 + jw) * 64 + u] * basep[(k + d) * 70 + jw];
      htile[(lr0 + k) * 64 + u] = acc;
    }
  }
  __syncthreads();
  int u2 = tid % 128, rg = tid / 128;
  float acc2[8];
  float bv = bf[u2];
#pragma unroll
  for (int k = 0; k < 8; ++k) acc2[k] = bv;
#pragma unroll 2
  for (int w0 = 0; w0 < 64; w0 += 4) {
    float m0 = Wf[(w0 + 0) * 128 + u2];
    float m1 = Wf[(w0 + 1) * 128 + u2];
    float m2 = Wf[(w0 + 2) * 128 + u2];
    float m3 = Wf[(w0 + 3) * 128 + u2];
    const float* xs = &htile[(rg * 8) * 64 + w0];
#pragma unroll
    for (int k = 0; k < 8; ++k) {
      float4 h4 = *(const float4*)(xs + k * 64);
      acc2[k] += m0 * h4.x + m1 * h4.y + m2 * h4.z + m3 * h4.w;
    }
  }
#pragma unroll
  for (int k = 0; k < 8; ++k)
    out[(size_t)(bstart + rg * 8 + k) * 128 + u2] = acc2[k];
}

// ------------------ standalone mean aggregation (agg3, agg6) ----------------
template <int DH>
__global__ __launch_bounds__(256) void k_agg(const float* __restrict__ yz,
                                             const int* __restrict__ csr,
                                             const int* __restrict__ rowptr,
                                             const float* __restrict__ invdeg,
                                             const float* __restrict__ bl,
                                             float* __restrict__ out, int N) {
  constexpr int FV = DH / 4;
  constexpr int G  = 64 / FV;
  constexpr int S4 = DH / 2;
  constexpr int CAP = 256;
  __shared__ int idxs[4 * CAP];
  int wid = threadIdx.x >> 6, lane = threadIdx.x & 63;
  int node = blockIdx.x * 4 + wid;
  int beg = rowptr[node], end = rowptr[node + 1];
  int cnt = end - beg;
  int m = cnt < CAP ? cnt : CAP;
  int* my = &idxs[wid * CAP];
  for (int k = lane; k < m; k += 64) my[k] = csr[beg + k];
  __syncthreads();
  int g = lane / FV, f = lane % FV;
  const float4* yz4 = (const float4*)yz;
  float a0x=0,a0y=0,a0z=0,a0w=0, a1x=0,a1y=0,a1z=0,a1w=0;
  float a2x=0,a2y=0,a2z=0,a2w=0, a3x=0,a3y=0,a3z=0,a3w=0;
  int j = g;
  for (; j + 3 * G < m; j += 4 * G) {
    int s0 = my[j], s1 = my[j + G], s2 = my[j + 2 * G], s3 = my[j + 3 * G];
    float4 v0 = yz4[(size_t)s0 * S4 + f];
    float4 v1 = yz4[(size_t)s1 * S4 + f];
    float4 v2 = yz4[(size_t)s2 * S4 + f];
    float4 v3 = yz4[(size_t)s3 * S4 + f];
    a0x += v0.x; a0y += v0.y; a0z += v0.z; a0w += v0.w;
    a1x += v1.x; a1y += v1.y; a1z += v1.z; a1w += v1.w;
    a2x += v2.x; a2y += v2.y; a2z += v2.z; a2w += v2.w;
    a3x += v3.x; a3y += v3.y; a3z += v3.z; a3w += v3.w;
  }
  for (; j < m; j += G) {
    int s0 = my[j];
    float4 v0 = yz4[(size_t)s0 * S4 + f];
    a0x += v0.x; a0y += v0.y; a0z += v0.z; a0w += v0.w;
  }
  for (int jj = beg + CAP + g; jj < end; jj += G) {
    int s0 = csr[jj];
    float4 v0 = yz4[(size_t)s0 * S4 + f];
    a0x += v0.x; a0y += v0.y; a0z += v0.z; a0w += v0.w;
  }
  float ax = (a0x + a1x) + (a2x + a3x);
  float ay = (a0y + a1y) + (a2y + a3y);
  float az = (a0z + a1z) + (a2z + a3z);
  float aw = (a0w + a1w) + (a2w + a3w);
#pragma unroll
  for (int mm = FV; mm < 64; mm <<= 1) {
    ax += __shfl_xor(ax, mm, 64);
    ay += __shfl_xor(ay, mm, 64);
    az += __shfl_xor(az, mm, 64);
    aw += __shfl_xor(aw, mm, 64);
  }
  if (g == 0) {
    float4 root = yz4[(size_t)node * S4 + FV + f];
    float4 bv = ((const float4*)bl)[f];
    float id = invdeg[node];
    float4 o;
    o.x = ax * id + bv.x + root.x;
    o.y = ay * id + bv.y + root.y;
    o.z = az * id + bv.z + root.z;
    o.w = aw * id + bv.w + root.w;
    ((float4*)out)[(size_t)node * FV + f] = o;
  }
}

// ------------------------------- launcher -----------------------------------
extern "C" void kernel_launch(void* const* d_in, const int* in_sizes, int n_in,
                              void* d_out, int out_size, void* d_ws, size_t ws_size,
                              hipStream_t stream) {
  const int N = NN, E = NE;
  const float* x   = (const float*)d_in[0];
  const int*   ei  = (const int*)d_in[1];
  const float* Wl1 = (const float*)d_in[2];
  const float* bl1 = (const float*)d_in[3];
  const float* Wr1 = (const float*)d_in[4];
  const float* Wl2 = (const float*)d_in[5];
  const float* bl2 = (const float*)d_in[6];
  const float* Wr2 = (const float*)d_in[7];
  const float* Wl3 = (const float*)d_in[8];
  const float* bl3 = (const float*)d_in[9];
  const float* Wr3 = (const float*)d_in[10];
  const float* Wc1 = (const float*)d_in[11];
  const float* bc1 = (const float*)d_in[12];
  const float* Wc2 = (const float*)d_in[13];
  const float* bc2 = (const float*)d_in[14];
  const float* Wc3 = (const float*)d_in[15];
  const float* bc3 = (const float*)d_in[16];
  const float* W2  = (const float*)d_in[17];
  const float* b2  = (const float*)d_in[18];

  char* ws = (char*)d_ws;
  size_t off = 0;
  auto alloc = [&](size_t bytes) -> void* {
    off = (off + 255) & ~(size_t)255;
    void* p = ws + off;
    off += bytes;
    return p;
  };
  int*   eflag  = (int*)alloc(4);
  int*   rowptr = (int*)alloc((size_t)(N + 1) * 4);
  int*   cursor = (int*)alloc((size_t)N * 4);
  float* invdeg = (float*)alloc((size_t)N * 4);
  int*   csr    = (int*)alloc((size_t)E * 4);
  unsigned long long* ebuf = (unsigned long long*)alloc((size_t)E * 8);
  int*   bcur   = (int*)alloc(128 * 4);
  int*   partial= (int*)alloc(128 * 4);
  int*   prefix = (int*)alloc(128 * 4);
  float* Wt1    = (float*)alloc(128 * 128 * 4);
  float* Wt2    = (float*)alloc(64 * 128 * 4);
  float* Wt3    = (float*)alloc(64 * 64 * 4);
  float* W2t    = (float*)alloc(64 * 64 * 4);
  float* Wf     = (float*)alloc(64 * 128 * 4);
  float* bf     = (float*)alloc(128 * 4);
  float* T729   = (float*)alloc(729 * 4);
  float* M5T    = (float*)alloc(15680 * 4);
  float* beta5  = (float*)alloc(320 * 4);
  float* yzA    = (float*)alloc((size_t)N * 128 * 4);
  float* yzB    = (float*)alloc((size_t)N * 128 * 4);
  float* hA     = (float*)alloc((size_t)N * 64 * 4);
  (void)ws_size; (void)in_sizes; (void)n_in; (void)out_size;

  const int gE = (E + 255) / 256;    // 2500
  const int gF = N / 16;             // 1250
  const int gA = N / 4;              // 5000
  const int gS = (N + 255) / 256;    // 79
  const int gP = (E + 4095) / 4096;  // 157

  // CSR build (once; shared by all 6 sage layers)
  k_init<<<gS, 256, 0, stream>>>(ei, cursor, eflag, N);
  k_hist<<<gE, 256, 0, stream>>>(ei, eflag, cursor, E);
  k_scanA<<<gS, 256, 0, stream>>>(cursor, partial, N);
  k_scanB<<<1, 128, 0, stream>>>(partial, prefix, rowptr, gS, E, N);
  k_scanC<<<gS, 256, 0, stream>>>(cursor, prefix, rowptr, cursor, invdeg, bcur, N);
  k_part<<<gP, 256, 0, stream>>>(ei, eflag, bcur, ebuf, E);
  k_scatter2<<<gE, 256, 0, stream>>>(ebuf, cursor, csr, E);

  // weight prep + conv composite build
  k_wtransA<<<128, 256, 0, stream>>>(Wl1, Wr1, Wl2, Wr2, Wl3, Wr3, W2,
                                     Wt1, Wt2, Wt3, W2t);
  k_setup2<<<39, 256, 0, stream>>>(Wc1, Wc2, Wc3, bc1, bc2, bc3, W2t, Wt2, b2,
                                   T729, beta5, Wf, bf);
  k_m5<<<62, 256, 0, stream>>>(T729, M5T);

  // sage1 transform
  k_gemm<128, 128><<<gF, 256, 0, stream>>>(x, Wt1, nullptr, yzA, N);
  // [agg1 + sage2-transform]
  k_fused<128><<<gF, 256, 0, stream>>>(yzA, csr, rowptr, invdeg, bl1, Wt2, yzB, N);
  // [agg2 + sage3-transform]
  k_fused<128><<<gF, 256, 0, stream>>>(yzB, csr, rowptr, invdeg, bl2, Wt2, yzA, N);
  // agg3 -> hA
  k_agg<64><<<gA, 256, 0, stream>>>(yzA, csr, rowptr, invdeg, bl2, hA, N);
  // [conv-composite + residual + linear2 + sage4-transform]
  k_applyfused<<<gF, 256, 0, stream>>>(hA, M5T, beta5, Wf, bf, yzB, N);
  // [agg4 + sage5-transform]
  k_fused<128><<<gF, 256, 0, stream>>>(yzB, csr, rowptr, invdeg, bl2, Wt2, yzA, N);
  // [agg5 + sage6-transform]
  k_fused<64><<<gF, 256, 0, stream>>>(yzA, csr, rowptr, invdeg, bl2, Wt3, yzB, N);
  // agg6 -> d_out (32-dim)
  k_agg<32><<<gA, 256, 0, stream>>>(yzB, csr, rowptr, invdeg, bl3, (float*)d_out, N);
}